// Round 1
// baseline (412.981 us; speedup 1.0000x reference)
//
#include <hip/hip_runtime.h>
#include <cstdint>
#include <cstddef>

// ---------------------------------------------------------------------------
// CBSA: x[8,256,64,64] -> proj GEMM -> pool -> cross-attn (keep attn) ->
// self-attn -> G = step_x * xd2 @ W_out slice -> out = G^T @ attn + b_out
// All fp32 (threshold 8.1e-4 abs is ~2% of |out|max; bf16 too risky round 1).
// ---------------------------------------------------------------------------

#define SCALE 0.125f  // 64^-0.5

// Canonical fp32 GEMM: C[b][M][N] = sum_k AT[k][M] * B[k][N]  (+bias over M)
// AT row stride = M (A transposed, k-major), B row stride = N.
// BM=BN=128, BK=8, 256 threads, 8x8 micro-tile (split 4+4 to avoid conflicts).
__global__ __launch_bounds__(256) void gemm128(
    const float* __restrict__ AT, long long at_bs,
    const float* __restrict__ B, long long b_bs,
    float* __restrict__ C, long long c_bs,
    int M, int N, int K, const float* __restrict__ bias) {
  __shared__ float As[8][128];
  __shared__ float Bs[8][128];
  int bz = blockIdx.z;
  const float* At = AT + (size_t)bz * at_bs;
  const float* Bt = B + (size_t)bz * b_bs;
  float* Ct = C + (size_t)bz * c_bs;
  int m0 = blockIdx.y * 128, n0 = blockIdx.x * 128;
  int t = threadIdx.x;
  int tx = t & 15, ty = t >> 4;
  int lk = t >> 5;          // 0..7
  int lm = (t & 31) * 4;    // 0..124
  float acc[8][8];
#pragma unroll
  for (int i = 0; i < 8; i++)
#pragma unroll
    for (int j = 0; j < 8; j++) acc[i][j] = 0.0f;

  for (int k0 = 0; k0 < K; k0 += 8) {
    float4 av = *(const float4*)(At + (size_t)(k0 + lk) * M + m0 + lm);
    float4 bv = *(const float4*)(Bt + (size_t)(k0 + lk) * N + n0 + lm);
    __syncthreads();  // previous iter's reads done before overwrite
    *(float4*)&As[lk][lm] = av;
    *(float4*)&Bs[lk][lm] = bv;
    __syncthreads();
#pragma unroll
    for (int k = 0; k < 8; k++) {
      float4 a0 = *(const float4*)&As[k][ty * 4];
      float4 a1 = *(const float4*)&As[k][64 + ty * 4];
      float4 b0 = *(const float4*)&Bs[k][tx * 4];
      float4 b1 = *(const float4*)&Bs[k][64 + tx * 4];
      float a[8] = {a0.x, a0.y, a0.z, a0.w, a1.x, a1.y, a1.z, a1.w};
      float bb[8] = {b0.x, b0.y, b0.z, b0.w, b1.x, b1.y, b1.z, b1.w};
#pragma unroll
      for (int i = 0; i < 8; i++)
#pragma unroll
        for (int j = 0; j < 8; j++) acc[i][j] += a[i] * bb[j];
    }
  }
#pragma unroll
  for (int i = 0; i < 8; i++) {
    int mm = m0 + ((i < 4) ? (ty * 4 + i) : (64 + ty * 4 + i - 4));
    float bi = bias ? bias[mm] : 0.0f;
    float4 o0 = make_float4(acc[i][0] + bi, acc[i][1] + bi, acc[i][2] + bi, acc[i][3] + bi);
    float4 o1 = make_float4(acc[i][4] + bi, acc[i][5] + bi, acc[i][6] + bi, acc[i][7] + bi);
    *(float4*)(Ct + (size_t)mm * N + n0 + tx * 4) = o0;
    *(float4*)(Ct + (size_t)mm * N + n0 + 64 + tx * 4) = o1;
  }
}

// rep[b][p][i] = mean over the 8x8 spatial block of proj[b][n][i]
__global__ __launch_bounds__(256) void pool_k(const float* __restrict__ proj,
                                              float* __restrict__ rep) {
  int bp = blockIdx.x;
  int b = bp >> 6, p = bp & 63;
  int py = p >> 3, px = p & 7;
  int t = threadIdx.x;
#pragma unroll
  for (int r = 0; r < 2; r++) {
    int i = t + r * 256;
    float s = 0.0f;
    for (int dy = 0; dy < 8; dy++) {
      int hh = py * 8 + dy;
#pragma unroll
      for (int dx = 0; dx < 8; dx++) {
        int n = hh * 64 + px * 8 + dx;
        s += proj[((size_t)(b * 4096 + n)) * 512 + i];
      }
    }
    rep[((size_t)(b * 64 + p)) * 512 + i] = s * 0.015625f;
  }
}

// dots[bh][m][n0..n0+64) = SCALE * q[m] . k[n]   (raw, pre-softmax)
__global__ __launch_bounds__(256) void dots_k(const float* __restrict__ rep,
                                              const float* __restrict__ proj,
                                              float* __restrict__ attn) {
  __shared__ float Qs[64][68];
  __shared__ float Ks[64][68];
  int bh = blockIdx.x, nt = blockIdx.y;
  int b = bh >> 3, h = bh & 7;
  int n0 = nt * 64;
  int t = threadIdx.x;
  int mi = t >> 2, dq = (t & 3) * 16;
  const float* qsrc = rep + ((size_t)(b * 64 + mi)) * 512 + h * 64 + dq;
  const float* ksrc = proj + ((size_t)(b * 4096 + n0 + mi)) * 512 + h * 64 + dq;
#pragma unroll
  for (int j = 0; j < 4; j++) {
    float4 v = *(const float4*)(qsrc + j * 4);
    Qs[dq + j * 4 + 0][mi] = v.x; Qs[dq + j * 4 + 1][mi] = v.y;
    Qs[dq + j * 4 + 2][mi] = v.z; Qs[dq + j * 4 + 3][mi] = v.w;
    float4 w = *(const float4*)(ksrc + j * 4);
    Ks[dq + j * 4 + 0][mi] = w.x; Ks[dq + j * 4 + 1][mi] = w.y;
    Ks[dq + j * 4 + 2][mi] = w.z; Ks[dq + j * 4 + 3][mi] = w.w;
  }
  __syncthreads();
  int tx = t & 15, ty = t >> 4;
  float acc[4][4] = {};
#pragma unroll
  for (int k = 0; k < 64; k++) {
    float4 a = *(const float4*)&Qs[k][ty * 4];
    float4 bv = *(const float4*)&Ks[k][tx * 4];
    float aa[4] = {a.x, a.y, a.z, a.w};
    float bb[4] = {bv.x, bv.y, bv.z, bv.w};
#pragma unroll
    for (int i = 0; i < 4; i++)
#pragma unroll
      for (int j = 0; j < 4; j++) acc[i][j] += aa[i] * bb[j];
  }
#pragma unroll
  for (int i = 0; i < 4; i++) {
    float4 o = make_float4(acc[i][0] * SCALE, acc[i][1] * SCALE,
                           acc[i][2] * SCALE, acc[i][3] * SCALE);
    *(float4*)(attn + ((size_t)bh * 64 + ty * 4 + i) * 4096 + n0 + tx * 4) = o;
  }
}

// in-place row softmax over 4096 elements; one block per row
__global__ __launch_bounds__(256) void softmax_k(float* __restrict__ attn) {
  size_t row = blockIdx.x;
  float* p = attn + row * 4096;
  int t = threadIdx.x;
  __shared__ float red[8];
  float v[16];
  float mx = -3.4e38f;
#pragma unroll
  for (int j = 0; j < 16; j++) {
    v[j] = p[t + j * 256];
    mx = fmaxf(mx, v[j]);
  }
#pragma unroll
  for (int o = 32; o; o >>= 1) mx = fmaxf(mx, __shfl_xor(mx, o));
  if ((t & 63) == 0) red[t >> 6] = mx;
  __syncthreads();
  mx = fmaxf(fmaxf(red[0], red[1]), fmaxf(red[2], red[3]));
  float s = 0.0f;
#pragma unroll
  for (int j = 0; j < 16; j++) {
    v[j] = __expf(v[j] - mx);
    s += v[j];
  }
#pragma unroll
  for (int o = 32; o; o >>= 1) s += __shfl_xor(s, o);
  if ((t & 63) == 0) red[4 + (t >> 6)] = s;
  __syncthreads();
  float r = 1.0f / (red[4] + red[5] + red[6] + red[7]);
#pragma unroll
  for (int j = 0; j < 16; j++) p[t + j * 256] = v[j] * r;
}

// partial[s][bh][m][d] = sum over n in [s*512,(s+1)*512) of attn[m][n]*v[n][d]
__global__ __launch_bounds__(256) void pv_k(const float* __restrict__ attn,
                                            const float* __restrict__ proj,
                                            float* __restrict__ partial) {
  __shared__ float As[32][68];
  __shared__ float Bs[32][68];
  int bh = blockIdx.x, s = blockIdx.y;
  int b = bh >> 3, h = bh & 7;
  int t = threadIdx.x;
  int tx = t & 15, ty = t >> 4;
  int am = t >> 2, akq = (t & 3) * 8;
  int vk = t >> 3, vdq = (t & 7) * 8;
  float acc[4][4] = {};
  for (int kt = 0; kt < 16; kt++) {
    int n0 = s * 512 + kt * 32;
#pragma unroll
    for (int j = 0; j < 2; j++) {
      float4 v = *(const float4*)(attn + ((size_t)bh * 64 + am) * 4096 + n0 + akq + j * 4);
      As[akq + j * 4 + 0][am] = v.x; As[akq + j * 4 + 1][am] = v.y;
      As[akq + j * 4 + 2][am] = v.z; As[akq + j * 4 + 3][am] = v.w;
      float4 w = *(const float4*)(proj + ((size_t)(b * 4096 + n0 + vk)) * 512 + h * 64 + vdq + j * 4);
      *(float4*)&Bs[vk][vdq + j * 4] = w;
    }
    __syncthreads();
#pragma unroll
    for (int k = 0; k < 32; k++) {
      float4 a = *(const float4*)&As[k][ty * 4];
      float4 bv = *(const float4*)&Bs[k][tx * 4];
      float aa[4] = {a.x, a.y, a.z, a.w};
      float bb[4] = {bv.x, bv.y, bv.z, bv.w};
#pragma unroll
      for (int i = 0; i < 4; i++)
#pragma unroll
        for (int j = 0; j < 4; j++) acc[i][j] += aa[i] * bb[j];
    }
    __syncthreads();
  }
#pragma unroll
  for (int i = 0; i < 4; i++) {
    *(float4*)(partial + ((size_t)(s * 64 + bh) * 64 + ty * 4 + i) * 64 + tx * 4) =
        make_float4(acc[i][0], acc[i][1], acc[i][2], acc[i][3]);
  }
}

// rep2[bh][m][d] = rep_h + step_rep * sum_s partial
__global__ __launch_bounds__(256) void rep2_k(const float* __restrict__ partial,
                                              const float* __restrict__ rep,
                                              const float* __restrict__ step_rep,
                                              float* __restrict__ rep2) {
  int bh = blockIdx.x;
  int b = bh >> 3, h = bh & 7;
  float sr = step_rep[h];
  for (int idx = threadIdx.x; idx < 4096; idx += 256) {
    int m = idx >> 6, d = idx & 63;
    float s = 0.0f;
#pragma unroll
    for (int ss = 0; ss < 8; ss++)
      s += partial[((size_t)(ss * 64 + bh) * 64 + m) * 64 + d];
    rep2[((size_t)bh * 64 + m) * 64 + d] =
        rep[((size_t)(b * 64 + m)) * 512 + h * 64 + d] + sr * s;
  }
}

// stage-2 self-attn among 64 tokens + fold step_x and W_out slice into G
__global__ __launch_bounds__(256) void stage2_k(const float* __restrict__ rep2,
                                                const float* __restrict__ Wo,
                                                const float* __restrict__ step_x,
                                                float* __restrict__ G) {
  __shared__ float T[64][68];   // T[d][m] = rep2[m][d]
  __shared__ float P[64][68];   // scores -> probs -> then reused as X[m][d]
  __shared__ float Wl[64][68];  // W_out tile [d][co-block]
  int bh = blockIdx.x, h = bh & 7;
  int t = threadIdx.x;
  int mi = t >> 2, dq = (t & 3) * 16;
#pragma unroll
  for (int j = 0; j < 4; j++) {
    float4 v = *(const float4*)(rep2 + ((size_t)bh * 64 + mi) * 64 + dq + j * 4);
    T[dq + j * 4 + 0][mi] = v.x; T[dq + j * 4 + 1][mi] = v.y;
    T[dq + j * 4 + 2][mi] = v.z; T[dq + j * 4 + 3][mi] = v.w;
  }
  __syncthreads();
  int tx = t & 15, ty = t >> 4;
  {
    float acc[4][4] = {};
#pragma unroll
    for (int k = 0; k < 64; k++) {
      float4 a = *(const float4*)&T[k][ty * 4];
      float4 bv = *(const float4*)&T[k][tx * 4];
      float aa[4] = {a.x, a.y, a.z, a.w};
      float bb[4] = {bv.x, bv.y, bv.z, bv.w};
#pragma unroll
      for (int i = 0; i < 4; i++)
#pragma unroll
        for (int j = 0; j < 4; j++) acc[i][j] += aa[i] * bb[j];
    }
#pragma unroll
    for (int i = 0; i < 4; i++)
      *(float4*)&P[ty * 4 + i][tx * 4] =
          make_float4(acc[i][0] * SCALE, acc[i][1] * SCALE, acc[i][2] * SCALE, acc[i][3] * SCALE);
  }
  __syncthreads();
  if (t < 64) {  // wave 0: one row each
    float mx = -3.4e38f;
    for (int n = 0; n < 64; n++) mx = fmaxf(mx, P[t][n]);
    float s = 0.0f;
    for (int n = 0; n < 64; n++) {
      float e = __expf(P[t][n] - mx);
      P[t][n] = e;
      s += e;
    }
    float r = 1.0f / s;
    for (int n = 0; n < 64; n++) P[t][n] *= r;
  }
  __syncthreads();
  // xd2[m][d] = sum_n P[m][n] * rep2[n][d]   (rep2[n][d] = T[d][n])
  float xacc[4][4] = {};
#pragma unroll
  for (int k = 0; k < 64; k++) {
    float aa[4], bb[4];
#pragma unroll
    for (int i = 0; i < 4; i++) {
      aa[i] = P[ty * 4 + i][k];
      bb[i] = T[tx * 4 + i][k];
    }
#pragma unroll
    for (int i = 0; i < 4; i++)
#pragma unroll
      for (int j = 0; j < 4; j++) xacc[i][j] += aa[i] * bb[j];
  }
  __syncthreads();  // all P reads done
#pragma unroll
  for (int i = 0; i < 4; i++)
    *(float4*)&P[ty * 4 + i][tx * 4] =
        make_float4(xacc[i][0], xacc[i][1], xacc[i][2], xacc[i][3]);
  // P now holds X[m][d] = xd2
  float sxh = step_x[h];
  int wk = t >> 2, wcq = (t & 3) * 16;
  for (int cb = 0; cb < 4; cb++) {
    __syncthreads();  // X writes visible / previous Wl reads done
#pragma unroll
    for (int j = 0; j < 4; j++)
      *(float4*)&Wl[wk][wcq + j * 4] =
          *(const float4*)(Wo + ((size_t)(h * 64 + wk)) * 256 + cb * 64 + wcq + j * 4);
    __syncthreads();
    float g[4][4] = {};
#pragma unroll
    for (int k = 0; k < 64; k++) {
      float aa[4];
#pragma unroll
      for (int i = 0; i < 4; i++) aa[i] = P[ty * 4 + i][k];
      float4 bv = *(const float4*)&Wl[k][tx * 4];
      float bb[4] = {bv.x, bv.y, bv.z, bv.w};
#pragma unroll
      for (int i = 0; i < 4; i++)
#pragma unroll
        for (int j = 0; j < 4; j++) g[i][j] += aa[i] * bb[j];
    }
#pragma unroll
    for (int i = 0; i < 4; i++)
      *(float4*)(G + ((size_t)bh * 64 + ty * 4 + i) * 256 + cb * 64 + tx * 4) =
          make_float4(g[i][0] * sxh, g[i][1] * sxh, g[i][2] * sxh, g[i][3] * sxh);
  }
}

extern "C" void kernel_launch(void* const* d_in, const int* in_sizes, int n_in,
                              void* d_out, int out_size, void* d_ws, size_t ws_size,
                              hipStream_t stream) {
  const float* x = (const float*)d_in[0];     // [8,256,64,64] = [b][c][n]
  const float* Wp = (const float*)d_in[1];    // [256,512]
  const float* srep = (const float*)d_in[2];  // [8]
  const float* sx = (const float*)d_in[3];    // [8]
  const float* Wo = (const float*)d_in[4];    // [512,256]
  const float* bo = (const float*)d_in[5];    // [256]
  float* out = (float*)d_out;                 // [8,256,4096]

  float* ws = (float*)d_ws;
  float* proj = ws;                                  // 8*4096*512
  float* attn = proj + (size_t)8 * 4096 * 512;       // 8*512*4096
  float* rep = attn + (size_t)8 * 512 * 4096;        // 8*64*512
  float* rep2 = rep + (size_t)8 * 64 * 512;          // 64*64*64
  float* partial = rep2 + (size_t)64 * 64 * 64;      // 8*64*64*64
  float* G = partial + (size_t)8 * 64 * 64 * 64;     // 8*512*256

  // proj[b][n][i] = sum_c x[b][c][n] * Wp[c][i]   M=4096 N=512 K=256
  gemm128<<<dim3(4, 32, 8), 256, 0, stream>>>(
      x, (long long)4096 * 256, Wp, 0, proj, (long long)4096 * 512,
      4096, 512, 256, nullptr);
  pool_k<<<dim3(512), 256, 0, stream>>>(proj, rep);
  dots_k<<<dim3(64, 64), 256, 0, stream>>>(rep, proj, attn);
  softmax_k<<<dim3(4096), 256, 0, stream>>>(attn);
  pv_k<<<dim3(64, 8), 256, 0, stream>>>(attn, proj, partial);
  rep2_k<<<dim3(64), 256, 0, stream>>>(partial, rep, srep, rep2);
  stage2_k<<<dim3(64), 256, 0, stream>>>(rep2, Wo, sx, G);
  // out[b][co][n] = sum_k G[b][k][co] * attn[b][k][n] + bo[co]  M=256 N=4096 K=512
  gemm128<<<dim3(32, 2, 8), 256, 0, stream>>>(
      G, (long long)512 * 256, attn, (long long)512 * 4096, out,
      (long long)256 * 4096, 256, 4096, 512, bo);
}

// Round 2
// 321.402 us; speedup vs baseline: 1.2849x; 1.2849x over previous
//
#include <hip/hip_runtime.h>
#include <cstdint>
#include <cstddef>

// ---------------------------------------------------------------------------
// CBSA round 2: big GEMMs -> split-bf16 MFMA (hi/lo two-term split, 3 MFMA per
// product, fp32 accumulate). Operands made K-contiguous via fused
// transpose+split passes. Everything else unchanged from round 1.
// ---------------------------------------------------------------------------

#define SCALE 0.125f  // 64^-0.5

typedef __attribute__((ext_vector_type(8))) short bf16x8;   // 8 bf16 = 4 VGPR
typedef __attribute__((ext_vector_type(4))) float f32x4;

// ---- bf16 split helpers (manual RNE; no NaN/inf in this workload) ----------
__device__ __forceinline__ unsigned short f2bf(float x) {
  unsigned int u = __float_as_uint(x);
  u += 0x7FFFu + ((u >> 16) & 1u);
  return (unsigned short)(u >> 16);
}
__device__ __forceinline__ float bf2f(unsigned short b) {
  return __uint_as_float(((unsigned int)b) << 16);
}
__device__ __forceinline__ void split2(float x, unsigned short& h, unsigned short& l) {
  h = f2bf(x);
  l = f2bf(x - bf2f(h));   // x - hi is exact in fp32
}

// ---- async global->LDS, 16B per lane (dest = wave-uniform base + lane*16) --
typedef const __attribute__((address_space(1))) unsigned int* gas_ptr;
typedef __attribute__((address_space(3))) unsigned int* las_ptr;
__device__ __forceinline__ void gload16(const void* g, void* l) {
  __builtin_amdgcn_global_load_lds((gas_ptr)(size_t)g,
                                   (las_ptr)(unsigned int)(size_t)l, 16, 0, 0);
}

// ---------------------------------------------------------------------------
// transpose + bf16-split: in fp32 [bz][R][C] row-major -> oh/ol bf16 [bz][C][R]
// ---------------------------------------------------------------------------
__global__ __launch_bounds__(256) void tsplit(
    const float* __restrict__ in, long long in_bs,
    unsigned short* __restrict__ oh, unsigned short* __restrict__ ol,
    long long o_bs, int R, int C) {
  __shared__ float T[32][33];
  int bz = blockIdx.z;
  const float* ip = in + (size_t)bz * in_bs;
  unsigned short* oph = oh + (size_t)bz * o_bs;
  unsigned short* opl = ol + (size_t)bz * o_bs;
  int c0 = blockIdx.x * 32, r0 = blockIdx.y * 32;
  int t = threadIdx.x;
  int col = t & 31, row8 = t >> 5;
#pragma unroll
  for (int i = 0; i < 4; i++)
    T[row8 + i * 8][col] = ip[(size_t)(r0 + row8 + i * 8) * C + c0 + col];
  __syncthreads();
#pragma unroll
  for (int i = 0; i < 4; i++) {
    float v = T[col][row8 + i * 8];               // = in[r0+col][c0+row8+8i]
    unsigned short h, l;
    split2(v, h, l);
    size_t o = (size_t)(c0 + row8 + i * 8) * R + r0 + col;
    oph[o] = h;
    opl[o] = l;
  }
}

// ---------------------------------------------------------------------------
// Split-bf16 MFMA GEMM: C[bz][M][N] = sum_k (Ah+Al)[m][k] * (Bh+Bl)[n][k]
// A: bf16 [M][K] row-major, B: bf16 [N][K] row-major (both K-contiguous).
// 128x128 tile, BK=32, 256 thr = 4 waves (each wave: 64x64 out, stages 1 array).
// LDS [row][4 slots of 8 bf16], slot XOR-swizzled by (row>>1)&3 on BOTH the
// pre-swizzled global source (for linear global_load_lds) and the ds_read.
// ---------------------------------------------------------------------------
__global__ __launch_bounds__(256) void gemm_mfma(
    const unsigned short* __restrict__ Ah, const unsigned short* __restrict__ Al,
    long long a_bs,
    const unsigned short* __restrict__ Bh, const unsigned short* __restrict__ Bl,
    long long b_bs,
    float* __restrict__ C, long long c_bs,
    int M, int N, int K, const float* __restrict__ bias) {
  __shared__ unsigned short lds[4][128][32];   // 0=Ah 1=Al 2=Bh 3=Bl, 32KB
  int bz = blockIdx.z;
  int m0 = blockIdx.y * 128, n0 = blockIdx.x * 128;
  int t = threadIdx.x;
  int wave = t >> 6, lane = t & 63;
  int wr = wave >> 1, wc = wave & 1;

  // staging: wave w stages array w. lane l -> row q = l>>2 (of 16-row slab),
  // LDS slot l&3; global k-chunk = slot ^ ((row>>1)&3)  (pre-swizzle).
  const unsigned short* src;
  int r0g;
  if (wave == 0)      { src = Ah + (size_t)bz * a_bs; r0g = m0; }
  else if (wave == 1) { src = Al + (size_t)bz * a_bs; r0g = m0; }
  else if (wave == 2) { src = Bh + (size_t)bz * b_bs; r0g = n0; }
  else                { src = Bl + (size_t)bz * b_bs; r0g = n0; }
  int q = lane >> 2;
  int chunk = (lane & 3) ^ ((q >> 1) & 3);
  const unsigned short* srow = src + (size_t)(r0g + q) * K + chunk * 8;

  // fragment read setup: lane holds (m or n) = fr, k = g*8..g*8+7
  int g = lane >> 4, fr = lane & 15;
  int slot = (g ^ ((fr >> 1) & 3)) * 8;        // (row>>1)&3 == (fr>>1)&3
  const unsigned short* aRow = &lds[0][wr * 64 + fr][slot];
  const unsigned short* bRow = &lds[2][wc * 64 + fr][slot];

  f32x4 acc[4][4];
  f32x4 zv = {0.f, 0.f, 0.f, 0.f};
#pragma unroll
  for (int i = 0; i < 4; i++)
#pragma unroll
    for (int j = 0; j < 4; j++) acc[i][j] = zv;

  for (int k0 = 0; k0 < K; k0 += 32) {
    __syncthreads();                            // prev iter's reads done
#pragma unroll
    for (int s = 0; s < 8; s++)
      gload16(srow + (size_t)(s * 16) * K + k0, &lds[wave][s * 16][0]);
    __syncthreads();                            // staging complete (vmcnt drain)
    bf16x8 af[2][4], bfv[2][4];
#pragma unroll
    for (int i = 0; i < 4; i++) {
      af[0][i]  = *(const bf16x8*)(aRow + i * 512);          // Ah, row +16*i
      af[1][i]  = *(const bf16x8*)(aRow + 4096 + i * 512);   // Al  (+128 rows)
      bfv[0][i] = *(const bf16x8*)(bRow + i * 512);          // Bh
      bfv[1][i] = *(const bf16x8*)(bRow + 4096 + i * 512);   // Bl
    }
#pragma unroll
    for (int i = 0; i < 4; i++)
#pragma unroll
      for (int j = 0; j < 4; j++) {
        acc[i][j] = __builtin_amdgcn_mfma_f32_16x16x32_bf16(af[0][i], bfv[0][j], acc[i][j], 0, 0, 0);
        acc[i][j] = __builtin_amdgcn_mfma_f32_16x16x32_bf16(af[0][i], bfv[1][j], acc[i][j], 0, 0, 0);
        acc[i][j] = __builtin_amdgcn_mfma_f32_16x16x32_bf16(af[1][i], bfv[0][j], acc[i][j], 0, 0, 0);
      }
  }
  // epilogue: D row = g*4 + reg, col = fr
  float* Cb = C + (size_t)bz * c_bs;
  int mBase = m0 + wr * 64 + g * 4;
  int nBase = n0 + wc * 64 + fr;
#pragma unroll
  for (int i = 0; i < 4; i++)
#pragma unroll
    for (int qd = 0; qd < 4; qd++) {
      int m = mBase + i * 16 + qd;
      float bi = bias ? bias[m] : 0.0f;
#pragma unroll
      for (int j = 0; j < 4; j++)
        Cb[(size_t)m * N + nBase + j * 16] = acc[i][j][qd] + bi;
    }
}

// ---------------------------------------------------------------------------
// rep[b][p][i] = mean over the 8x8 spatial block of proj[b][n][i]
// ---------------------------------------------------------------------------
__global__ __launch_bounds__(256) void pool_k(const float* __restrict__ proj,
                                              float* __restrict__ rep) {
  int bp = blockIdx.x;
  int b = bp >> 6, p = bp & 63;
  int py = p >> 3, px = p & 7;
  int t = threadIdx.x;
#pragma unroll
  for (int r = 0; r < 2; r++) {
    int i = t + r * 256;
    float s = 0.0f;
    for (int dy = 0; dy < 8; dy++) {
      int hh = py * 8 + dy;
#pragma unroll
      for (int dx = 0; dx < 8; dx++) {
        int n = hh * 64 + px * 8 + dx;
        s += proj[((size_t)(b * 4096 + n)) * 512 + i];
      }
    }
    rep[((size_t)(b * 64 + p)) * 512 + i] = s * 0.015625f;
  }
}

// dots[bh][m][n0..n0+64) = SCALE * q[m] . k[n]   (raw, pre-softmax)
__global__ __launch_bounds__(256) void dots_k(const float* __restrict__ rep,
                                              const float* __restrict__ proj,
                                              float* __restrict__ attn) {
  __shared__ float Qs[64][68];
  __shared__ float Ks[64][68];
  int bh = blockIdx.x, nt = blockIdx.y;
  int b = bh >> 3, h = bh & 7;
  int n0 = nt * 64;
  int t = threadIdx.x;
  int mi = t >> 2, dq = (t & 3) * 16;
  const float* qsrc = rep + ((size_t)(b * 64 + mi)) * 512 + h * 64 + dq;
  const float* ksrc = proj + ((size_t)(b * 4096 + n0 + mi)) * 512 + h * 64 + dq;
#pragma unroll
  for (int j = 0; j < 4; j++) {
    float4 v = *(const float4*)(qsrc + j * 4);
    Qs[dq + j * 4 + 0][mi] = v.x; Qs[dq + j * 4 + 1][mi] = v.y;
    Qs[dq + j * 4 + 2][mi] = v.z; Qs[dq + j * 4 + 3][mi] = v.w;
    float4 w = *(const float4*)(ksrc + j * 4);
    Ks[dq + j * 4 + 0][mi] = w.x; Ks[dq + j * 4 + 1][mi] = w.y;
    Ks[dq + j * 4 + 2][mi] = w.z; Ks[dq + j * 4 + 3][mi] = w.w;
  }
  __syncthreads();
  int tx = t & 15, ty = t >> 4;
  float acc[4][4] = {};
#pragma unroll
  for (int k = 0; k < 64; k++) {
    float4 a = *(const float4*)&Qs[k][ty * 4];
    float4 bv = *(const float4*)&Ks[k][tx * 4];
    float aa[4] = {a.x, a.y, a.z, a.w};
    float bb[4] = {bv.x, bv.y, bv.z, bv.w};
#pragma unroll
    for (int i = 0; i < 4; i++)
#pragma unroll
      for (int j = 0; j < 4; j++) acc[i][j] += aa[i] * bb[j];
  }
#pragma unroll
  for (int i = 0; i < 4; i++) {
    float4 o = make_float4(acc[i][0] * SCALE, acc[i][1] * SCALE,
                           acc[i][2] * SCALE, acc[i][3] * SCALE);
    *(float4*)(attn + ((size_t)bh * 64 + ty * 4 + i) * 4096 + n0 + tx * 4) = o;
  }
}

// in-place row softmax over 4096 elements; one block per row
__global__ __launch_bounds__(256) void softmax_k(float* __restrict__ attn) {
  size_t row = blockIdx.x;
  float* p = attn + row * 4096;
  int t = threadIdx.x;
  __shared__ float red[8];
  float v[16];
  float mx = -3.4e38f;
#pragma unroll
  for (int j = 0; j < 16; j++) {
    v[j] = p[t + j * 256];
    mx = fmaxf(mx, v[j]);
  }
#pragma unroll
  for (int o = 32; o; o >>= 1) mx = fmaxf(mx, __shfl_xor(mx, o));
  if ((t & 63) == 0) red[t >> 6] = mx;
  __syncthreads();
  mx = fmaxf(fmaxf(red[0], red[1]), fmaxf(red[2], red[3]));
  float s = 0.0f;
#pragma unroll
  for (int j = 0; j < 16; j++) {
    v[j] = __expf(v[j] - mx);
    s += v[j];
  }
#pragma unroll
  for (int o = 32; o; o >>= 1) s += __shfl_xor(s, o);
  if ((t & 63) == 0) red[4 + (t >> 6)] = s;
  __syncthreads();
  float r = 1.0f / (red[4] + red[5] + red[6] + red[7]);
#pragma unroll
  for (int j = 0; j < 16; j++) p[t + j * 256] = v[j] * r;
}

// partial[s][bh][m][d] = sum over n in [s*512,(s+1)*512) of attn[m][n]*v[n][d]
__global__ __launch_bounds__(256) void pv_k(const float* __restrict__ attn,
                                            const float* __restrict__ proj,
                                            float* __restrict__ partial) {
  __shared__ float As[32][68];
  __shared__ float Bs[32][68];
  int bh = blockIdx.x, s = blockIdx.y;
  int b = bh >> 3, h = bh & 7;
  int t = threadIdx.x;
  int tx = t & 15, ty = t >> 4;
  int am = t >> 2, akq = (t & 3) * 8;
  int vk = t >> 3, vdq = (t & 7) * 8;
  float acc[4][4] = {};
  for (int kt = 0; kt < 16; kt++) {
    int n0 = s * 512 + kt * 32;
#pragma unroll
    for (int j = 0; j < 2; j++) {
      float4 v = *(const float4*)(attn + ((size_t)bh * 64 + am) * 4096 + n0 + akq + j * 4);
      As[akq + j * 4 + 0][am] = v.x; As[akq + j * 4 + 1][am] = v.y;
      As[akq + j * 4 + 2][am] = v.z; As[akq + j * 4 + 3][am] = v.w;
      float4 w = *(const float4*)(proj + ((size_t)(b * 4096 + n0 + vk)) * 512 + h * 64 + vdq + j * 4);
      *(float4*)&Bs[vk][vdq + j * 4] = w;
    }
    __syncthreads();
#pragma unroll
    for (int k = 0; k < 32; k++) {
      float4 a = *(const float4*)&As[k][ty * 4];
      float4 bv = *(const float4*)&Bs[k][tx * 4];
      float aa[4] = {a.x, a.y, a.z, a.w};
      float bb[4] = {bv.x, bv.y, bv.z, bv.w};
#pragma unroll
      for (int i = 0; i < 4; i++)
#pragma unroll
        for (int j = 0; j < 4; j++) acc[i][j] += aa[i] * bb[j];
    }
    __syncthreads();
  }
#pragma unroll
  for (int i = 0; i < 4; i++) {
    *(float4*)(partial + ((size_t)(s * 64 + bh) * 64 + ty * 4 + i) * 64 + tx * 4) =
        make_float4(acc[i][0], acc[i][1], acc[i][2], acc[i][3]);
  }
}

// rep2[bh][m][d] = rep_h + step_rep * sum_s partial
__global__ __launch_bounds__(256) void rep2_k(const float* __restrict__ partial,
                                              const float* __restrict__ rep,
                                              const float* __restrict__ step_rep,
                                              float* __restrict__ rep2) {
  int bh = blockIdx.x;
  int b = bh >> 3, h = bh & 7;
  float sr = step_rep[h];
  for (int idx = threadIdx.x; idx < 4096; idx += 256) {
    int m = idx >> 6, d = idx & 63;
    float s = 0.0f;
#pragma unroll
    for (int ss = 0; ss < 8; ss++)
      s += partial[((size_t)(ss * 64 + bh) * 64 + m) * 64 + d];
    rep2[((size_t)bh * 64 + m) * 64 + d] =
        rep[((size_t)(b * 64 + m)) * 512 + h * 64 + d] + sr * s;
  }
}

// stage-2 self-attn among 64 tokens; writes GT split bf16: GT[b][co][k=h*64+m]
__global__ __launch_bounds__(256) void stage2_k(const float* __restrict__ rep2,
                                                const float* __restrict__ Wo,
                                                const float* __restrict__ step_x,
                                                unsigned short* __restrict__ GTh,
                                                unsigned short* __restrict__ GTl) {
  __shared__ float T[64][68];   // T[d][m] = rep2[m][d]
  __shared__ float P[64][68];   // scores -> probs -> then reused as X[m][d]
  __shared__ float Wl[64][68];  // W_out tile [d][co-block]
  int bh = blockIdx.x, h = bh & 7, b = bh >> 3;
  int t = threadIdx.x;
  int mi = t >> 2, dq = (t & 3) * 16;
#pragma unroll
  for (int j = 0; j < 4; j++) {
    float4 v = *(const float4*)(rep2 + ((size_t)bh * 64 + mi) * 64 + dq + j * 4);
    T[dq + j * 4 + 0][mi] = v.x; T[dq + j * 4 + 1][mi] = v.y;
    T[dq + j * 4 + 2][mi] = v.z; T[dq + j * 4 + 3][mi] = v.w;
  }
  __syncthreads();
  int tx = t & 15, ty = t >> 4;
  {
    float acc[4][4] = {};
#pragma unroll
    for (int k = 0; k < 64; k++) {
      float4 a = *(const float4*)&T[k][ty * 4];
      float4 bv = *(const float4*)&T[k][tx * 4];
      float aa[4] = {a.x, a.y, a.z, a.w};
      float bb[4] = {bv.x, bv.y, bv.z, bv.w};
#pragma unroll
      for (int i = 0; i < 4; i++)
#pragma unroll
        for (int j = 0; j < 4; j++) acc[i][j] += aa[i] * bb[j];
    }
#pragma unroll
    for (int i = 0; i < 4; i++)
      *(float4*)&P[ty * 4 + i][tx * 4] =
          make_float4(acc[i][0] * SCALE, acc[i][1] * SCALE, acc[i][2] * SCALE, acc[i][3] * SCALE);
  }
  __syncthreads();
  if (t < 64) {  // wave 0: one row each
    float mx = -3.4e38f;
    for (int n = 0; n < 64; n++) mx = fmaxf(mx, P[t][n]);
    float s = 0.0f;
    for (int n = 0; n < 64; n++) {
      float e = __expf(P[t][n] - mx);
      P[t][n] = e;
      s += e;
    }
    float r = 1.0f / s;
    for (int n = 0; n < 64; n++) P[t][n] *= r;
  }
  __syncthreads();
  // xd2[m][d] = sum_n P[m][n] * rep2[n][d]   (rep2[n][d] = T[d][n])
  float xacc[4][4] = {};
#pragma unroll
  for (int k = 0; k < 64; k++) {
    float aa[4], bb[4];
#pragma unroll
    for (int i = 0; i < 4; i++) {
      aa[i] = P[ty * 4 + i][k];
      bb[i] = T[tx * 4 + i][k];
    }
#pragma unroll
    for (int i = 0; i < 4; i++)
#pragma unroll
      for (int j = 0; j < 4; j++) xacc[i][j] += aa[i] * bb[j];
  }
  __syncthreads();  // all P reads done
#pragma unroll
  for (int i = 0; i < 4; i++)
    *(float4*)&P[ty * 4 + i][tx * 4] =
        make_float4(xacc[i][0], xacc[i][1], xacc[i][2], xacc[i][3]);
  // P now holds X[m][d] = xd2
  float sxh = step_x[h];
  int wk = t >> 2, wcq = (t & 3) * 16;
  for (int cb = 0; cb < 4; cb++) {
    __syncthreads();  // X writes visible / previous Wl reads done
#pragma unroll
    for (int j = 0; j < 4; j++)
      *(float4*)&Wl[wk][wcq + j * 4] =
          *(const float4*)(Wo + ((size_t)(h * 64 + wk)) * 256 + cb * 64 + wcq + j * 4);
    __syncthreads();
    float gacc[4][4] = {};
#pragma unroll
    for (int k = 0; k < 64; k++) {
      float aa[4];
#pragma unroll
      for (int i = 0; i < 4; i++) aa[i] = P[ty * 4 + i][k];
      float4 bv = *(const float4*)&Wl[k][tx * 4];
      float bb[4] = {bv.x, bv.y, bv.z, bv.w};
#pragma unroll
      for (int i = 0; i < 4; i++)
#pragma unroll
        for (int j = 0; j < 4; j++) gacc[i][j] += aa[i] * bb[j];
    }
#pragma unroll
    for (int i = 0; i < 4; i++)
#pragma unroll
      for (int j = 0; j < 4; j++) {
        float val = gacc[i][j] * sxh;
        size_t o = ((size_t)(b * 256 + cb * 64 + tx * 4 + j)) * 512 + h * 64 + ty * 4 + i;
        unsigned short hh, ll;
        split2(val, hh, ll);
        GTh[o] = hh;
        GTl[o] = ll;
      }
  }
}

extern "C" void kernel_launch(void* const* d_in, const int* in_sizes, int n_in,
                              void* d_out, int out_size, void* d_ws, size_t ws_size,
                              hipStream_t stream) {
  const float* x = (const float*)d_in[0];     // [8,256,4096]  ([b][c][n])
  const float* Wp = (const float*)d_in[1];    // [256,512]
  const float* srep = (const float*)d_in[2];  // [8]
  const float* sx = (const float*)d_in[3];    // [8]
  const float* Wo = (const float*)d_in[4];    // [512,256]
  const float* bo = (const float*)d_in[5];    // [256]
  float* out = (float*)d_out;                 // [8,256,4096]

  float* ws = (float*)d_ws;
  float* proj    = ws;                        // 16,777,216 f
  float* attn    = ws + 16777216;             // 16,777,216 f
  float* rep     = ws + 33554432;             // 262,144 f
  float* rep2    = ws + 33816576;             // 262,144 f
  float* partial = ws + 34078720;             // 2,097,152 f (aliased below)
  // aliases (lifetimes disjoint in stream order):
  unsigned short* xTh = (unsigned short*)attn;          // dead before dots writes attn
  unsigned short* xTl = xTh + 8388608;
  unsigned short* WpTh = (unsigned short*)partial;      // dead before pv writes partial
  unsigned short* WpTl = WpTh + 131072;
  unsigned short* GTh = (unsigned short*)partial;       // written after rep2_k reads partial
  unsigned short* GTl = GTh + 1048576;
  unsigned short* attnTh = (unsigned short*)proj;       // written after pv reads proj
  unsigned short* attnTl = attnTh + 16777216;

  // 1. x [b][256][4096] -> xT split [b][4096][256]
  tsplit<<<dim3(128, 8, 8), 256, 0, stream>>>(x, (long long)256 * 4096,
                                              xTh, xTl, (long long)4096 * 256, 256, 4096);
  // 2. Wp [256][512] -> WpT split [512][256]
  tsplit<<<dim3(16, 8, 1), 256, 0, stream>>>(Wp, 0, WpTh, WpTl, 0, 256, 512);
  // 3. proj[b][n][i] = xT[n][c] . WpT[i][c]   M=4096 N=512 K=256
  gemm_mfma<<<dim3(4, 32, 8), 256, 0, stream>>>(
      xTh, xTl, (long long)4096 * 256, WpTh, WpTl, 0,
      proj, (long long)4096 * 512, 4096, 512, 256, nullptr);
  pool_k<<<dim3(512), 256, 0, stream>>>(proj, rep);
  dots_k<<<dim3(64, 64), 256, 0, stream>>>(rep, proj, attn);
  softmax_k<<<dim3(4096), 256, 0, stream>>>(attn);
  pv_k<<<dim3(64, 8), 256, 0, stream>>>(attn, proj, partial);
  rep2_k<<<dim3(64), 256, 0, stream>>>(partial, rep, srep, rep2);
  stage2_k<<<dim3(64), 256, 0, stream>>>(rep2, Wo, sx, GTh, GTl);
  // 10. attn [b][512][4096] -> attnT split [b][4096][512]  (proj now dead)
  tsplit<<<dim3(128, 16, 8), 256, 0, stream>>>(attn, (long long)512 * 4096,
                                               attnTh, attnTl, (long long)4096 * 512, 512, 4096);
  // 11. out[b][co][n] = GT[co][k] . attnT[n][k] + bo[co]   M=256 N=4096 K=512
  gemm_mfma<<<dim3(32, 2, 8), 256, 0, stream>>>(
      GTh, GTl, (long long)256 * 512, attnTh, attnTl, (long long)4096 * 512,
      out, (long long)256 * 4096, 256, 4096, 512, bo);
}

// Round 3
// 253.605 us; speedup vs baseline: 1.6284x; 1.2673x over previous
//
#include <hip/hip_runtime.h>
#include <cstdint>
#include <cstddef>

// ---------------------------------------------------------------------------
// CBSA round 3: fused streaming attention (no-max softmax, normalizer folded
// into G), MFMA everywhere. P written directly transposed+split for the final
// GEMM. proj stored split-bf16 by the proj-GEMM epilogue.
// ---------------------------------------------------------------------------

#define SCALE 0.125f  // 64^-0.5

typedef __attribute__((ext_vector_type(8))) short bf16x8;    // 8 bf16 = 4 VGPR
typedef __attribute__((ext_vector_type(4))) float f32x4;
typedef __attribute__((ext_vector_type(16))) float f32x16;
typedef __attribute__((ext_vector_type(4))) unsigned int u32x4;

#define MFMA32(a, b, c) __builtin_amdgcn_mfma_f32_32x32x16_bf16(a, b, c, 0, 0, 0)
#define MFMA16(a, b, c) __builtin_amdgcn_mfma_f32_16x16x32_bf16(a, b, c, 0, 0, 0)

// ---- bf16 helpers (manual RNE; no NaN/inf in this workload) ----------------
__device__ __forceinline__ unsigned short f2bf(float x) {
  unsigned int u = __float_as_uint(x);
  u += 0x7FFFu + ((u >> 16) & 1u);
  return (unsigned short)(u >> 16);
}
__device__ __forceinline__ float bf2f(unsigned short b) {
  return __uint_as_float(((unsigned int)b) << 16);
}
__device__ __forceinline__ void split2(float x, unsigned short& h, unsigned short& l) {
  h = f2bf(x);
  l = f2bf(x - bf2f(h));
}
__device__ __forceinline__ unsigned int cvtpk(float lo, float hi_) {
  unsigned int r;
  asm("v_cvt_pk_bf16_f32 %0, %1, %2" : "=v"(r) : "v"(lo), "v"(hi_));
  return r;
}

// ---- async global->LDS, 16B per lane ---------------------------------------
typedef const __attribute__((address_space(1))) unsigned int* gas_ptr;
typedef __attribute__((address_space(3))) unsigned int* las_ptr;
__device__ __forceinline__ void gload16(const void* g, void* l) {
  __builtin_amdgcn_global_load_lds((gas_ptr)(size_t)g,
                                   (las_ptr)(unsigned int)(size_t)l, 16, 0, 0);
}

// ---------------------------------------------------------------------------
// transpose + bf16-split: in fp32 [bz][R][C] row-major -> oh/ol bf16 [bz][C][R]
// ---------------------------------------------------------------------------
__global__ __launch_bounds__(256) void tsplit(
    const float* __restrict__ in, long long in_bs,
    unsigned short* __restrict__ oh, unsigned short* __restrict__ ol,
    long long o_bs, int R, int C) {
  __shared__ float T[32][33];
  int bz = blockIdx.z;
  const float* ip = in + (size_t)bz * in_bs;
  unsigned short* oph = oh + (size_t)bz * o_bs;
  unsigned short* opl = ol + (size_t)bz * o_bs;
  int c0 = blockIdx.x * 32, r0 = blockIdx.y * 32;
  int t = threadIdx.x;
  int col = t & 31, row8 = t >> 5;
#pragma unroll
  for (int i = 0; i < 4; i++)
    T[row8 + i * 8][col] = ip[(size_t)(r0 + row8 + i * 8) * C + c0 + col];
  __syncthreads();
#pragma unroll
  for (int i = 0; i < 4; i++) {
    float v = T[col][row8 + i * 8];
    unsigned short h, l;
    split2(v, h, l);
    size_t o = (size_t)(c0 + row8 + i * 8) * R + r0 + col;
    oph[o] = h;
    opl[o] = l;
  }
}

// ---------------------------------------------------------------------------
// Split-bf16 MFMA GEMM (16x16x32): C = sum_k (Ah+Al)[m][k]*(Bh+Bl)[n][k]
// Output either fp32 (Cf, +bias) or split-bf16 (Ch/Cl).
// ---------------------------------------------------------------------------
__global__ __launch_bounds__(256) void gemm_mfma(
    const unsigned short* __restrict__ Ah, const unsigned short* __restrict__ Al,
    long long a_bs,
    const unsigned short* __restrict__ Bh, const unsigned short* __restrict__ Bl,
    long long b_bs,
    float* __restrict__ Cf, unsigned short* __restrict__ Ch,
    unsigned short* __restrict__ Cl, long long c_bs,
    int M, int N, int K, const float* __restrict__ bias) {
  __shared__ unsigned short lds[4][128][32];
  int bz = blockIdx.z;
  int m0 = blockIdx.y * 128, n0 = blockIdx.x * 128;
  int t = threadIdx.x;
  int wave = t >> 6, lane = t & 63;
  int wr = wave >> 1, wc = wave & 1;

  const unsigned short* src;
  int r0g;
  if (wave == 0)      { src = Ah + (size_t)bz * a_bs; r0g = m0; }
  else if (wave == 1) { src = Al + (size_t)bz * a_bs; r0g = m0; }
  else if (wave == 2) { src = Bh + (size_t)bz * b_bs; r0g = n0; }
  else                { src = Bl + (size_t)bz * b_bs; r0g = n0; }
  int q = lane >> 2;
  int chunk = (lane & 3) ^ ((q >> 1) & 3);
  const unsigned short* srow = src + (size_t)(r0g + q) * K + chunk * 8;

  int g = lane >> 4, fr = lane & 15;
  int slot = (g ^ ((fr >> 1) & 3)) * 8;
  const unsigned short* aRow = &lds[0][wr * 64 + fr][slot];
  const unsigned short* bRow = &lds[2][wc * 64 + fr][slot];

  f32x4 acc[4][4];
#pragma unroll
  for (int i = 0; i < 4; i++)
#pragma unroll
    for (int j = 0; j < 4; j++)
#pragma unroll
      for (int r = 0; r < 4; r++) acc[i][j][r] = 0.0f;

  for (int k0 = 0; k0 < K; k0 += 32) {
    __syncthreads();
#pragma unroll
    for (int s = 0; s < 8; s++)
      gload16(srow + (size_t)(s * 16) * K + k0, &lds[wave][s * 16][0]);
    __syncthreads();
    bf16x8 af[2][4], bfv[2][4];
#pragma unroll
    for (int i = 0; i < 4; i++) {
      af[0][i]  = *(const bf16x8*)(aRow + i * 512);
      af[1][i]  = *(const bf16x8*)(aRow + 4096 + i * 512);
      bfv[0][i] = *(const bf16x8*)(bRow + i * 512);
      bfv[1][i] = *(const bf16x8*)(bRow + 4096 + i * 512);
    }
#pragma unroll
    for (int i = 0; i < 4; i++)
#pragma unroll
      for (int j = 0; j < 4; j++) {
        acc[i][j] = MFMA16(af[0][i], bfv[0][j], acc[i][j]);
        acc[i][j] = MFMA16(af[0][i], bfv[1][j], acc[i][j]);
        acc[i][j] = MFMA16(af[1][i], bfv[0][j], acc[i][j]);
      }
  }
  int mBase = m0 + wr * 64 + g * 4;
  int nBase = n0 + wc * 64 + fr;
  if (Cf) {
    float* Cb = Cf + (size_t)bz * c_bs;
#pragma unroll
    for (int i = 0; i < 4; i++)
#pragma unroll
      for (int qd = 0; qd < 4; qd++) {
        int m = mBase + i * 16 + qd;
        float bi = bias ? bias[m] : 0.0f;
#pragma unroll
        for (int j = 0; j < 4; j++)
          Cb[(size_t)m * N + nBase + j * 16] = acc[i][j][qd] + bi;
      }
  } else {
    unsigned short* Chb = Ch + (size_t)bz * c_bs;
    unsigned short* Clb = Cl + (size_t)bz * c_bs;
#pragma unroll
    for (int i = 0; i < 4; i++)
#pragma unroll
      for (int qd = 0; qd < 4; qd++) {
        int m = mBase + i * 16 + qd;
#pragma unroll
        for (int j = 0; j < 4; j++) {
          unsigned short hh, ll;
          split2(acc[i][j][qd], hh, ll);
          Chb[(size_t)m * N + nBase + j * 16] = hh;
          Clb[(size_t)m * N + nBase + j * 16] = ll;
        }
      }
  }
}

// ---------------------------------------------------------------------------
// rep (pooled) from split proj -> split-bf16 rep
// ---------------------------------------------------------------------------
__global__ __launch_bounds__(256) void pool2_k(
    const unsigned short* __restrict__ projh, const unsigned short* __restrict__ projl,
    unsigned short* __restrict__ reph, unsigned short* __restrict__ repl) {
  int bp = blockIdx.x;
  int b = bp >> 6, p = bp & 63;
  int py = p >> 3, px = p & 7;
  int i0 = threadIdx.x * 2;
  float s0 = 0.0f, s1 = 0.0f;
  for (int dy = 0; dy < 8; dy++) {
    int hh = py * 8 + dy;
#pragma unroll
    for (int dx = 0; dx < 8; dx++) {
      int n = hh * 64 + px * 8 + dx;
      size_t o = ((size_t)(b * 4096 + n)) * 512 + i0;
      unsigned int wh = *(const unsigned int*)(projh + o);
      unsigned int wl = *(const unsigned int*)(projl + o);
      s0 += bf2f((unsigned short)wh) + bf2f((unsigned short)wl);
      s1 += bf2f((unsigned short)(wh >> 16)) + bf2f((unsigned short)(wl >> 16));
    }
  }
  s0 *= 0.015625f;
  s1 *= 0.015625f;
  unsigned short h0, l0, h1, l1;
  split2(s0, h0, l0);
  split2(s1, h1, l1);
  size_t ro = ((size_t)(b * 64 + p)) * 512 + i0;
  *(unsigned int*)(reph + ro) = (unsigned int)h0 | ((unsigned int)h1 << 16);
  *(unsigned int*)(repl + ro) = (unsigned int)l0 | ((unsigned int)l1 << 16);
}

// ---------------------------------------------------------------------------
// Fused attention: per (bh, s=512-key chunk): S^T = mfma(K,Q) (32x32x16,
// 3-term split), P = exp(S*SCALE) (no max-sub; safe: |S|<~1), write P
// transposed+split to PT, accumulate PV (3-term) and row-sums l.
// Wave w handles key subtiles {2w, 2w+1} (64 keys each).
// ---------------------------------------------------------------------------
__global__ __launch_bounds__(256) void fattn(
    const unsigned short* __restrict__ projh, const unsigned short* __restrict__ projl,
    const unsigned short* __restrict__ reph, const unsigned short* __restrict__ repl,
    unsigned short* __restrict__ PTh, unsigned short* __restrict__ PTl,
    float* __restrict__ pvpart, float* __restrict__ lpart) {
  int bh = blockIdx.x, s = blockIdx.y;
  int b = bh >> 3, h = bh & 7;
  int t = threadIdx.x;
  int wave = t >> 6, lane = t & 63;
  int lm = lane & 31, hi = lane >> 5;

  // Q B-frags: [mt][ks][hi/lo]; col m = mt*32+lm, k = ks*16 + hi*8 + j
  bf16x8 qf[2][4][2];
#pragma unroll
  for (int mt = 0; mt < 2; mt++)
#pragma unroll
    for (int ks = 0; ks < 4; ks++) {
      size_t qo = ((size_t)(b * 64 + mt * 32 + lm)) * 512 + h * 64 + ks * 16 + hi * 8;
      qf[mt][ks][0] = *(const bf16x8*)(reph + qo);
      qf[mt][ks][1] = *(const bf16x8*)(repl + qo);
    }

  f32x16 pv[2][2];
#pragma unroll
  for (int a = 0; a < 2; a++)
#pragma unroll
    for (int c = 0; c < 2; c++)
#pragma unroll
      for (int r = 0; r < 16; r++) pv[a][c][r] = 0.0f;
  float lsum0 = 0.0f, lsum1 = 0.0f;

  for (int sti = 0; sti < 2; sti++) {
    int n0 = s * 512 + (wave * 2 + sti) * 64;
    for (int nn = 0; nn < 64; nn += 32) {
      int nb = n0 + nn;
      f32x16 sa0, sa1;
#pragma unroll
      for (int r = 0; r < 16; r++) { sa0[r] = 0.0f; sa1[r] = 0.0f; }
#pragma unroll
      for (int ks = 0; ks < 4; ks++) {
        size_t ko = ((size_t)(b * 4096 + nb + lm)) * 512 + h * 64 + ks * 16 + hi * 8;
        bf16x8 kh = *(const bf16x8*)(projh + ko);
        bf16x8 kl = *(const bf16x8*)(projl + ko);
        sa0 = MFMA32(kh, qf[0][ks][0], sa0);
        sa0 = MFMA32(kh, qf[0][ks][1], sa0);
        sa0 = MFMA32(kl, qf[0][ks][0], sa0);
        sa1 = MFMA32(kh, qf[1][ks][0], sa1);
        sa1 = MFMA32(kh, qf[1][ks][1], sa1);
        sa1 = MFMA32(kl, qf[1][ks][0], sa1);
      }
      // exp (in place) + row-sum partials
#pragma unroll
      for (int r = 0; r < 16; r++) {
        sa0[r] = __expf(sa0[r] * SCALE); lsum0 += sa0[r];
        sa1[r] = __expf(sa1[r] * SCALE); lsum1 += sa1[r];
      }
      // PT store: n = nb + (r&3)+8*(r>>2)+4*hi; k = h*64 + mt*32 + lm
      {
        int kk0 = h * 64 + lm, kk1 = kk0 + 32;
#pragma unroll
        for (int r = 0; r < 16; r++) {
          int n = nb + (r & 3) + 8 * (r >> 2) + 4 * hi;
          size_t o = ((size_t)(b * 4096 + n)) * 512;
          float p0 = sa0[r], p1 = sa1[r];
          unsigned short h0 = f2bf(p0), h1 = f2bf(p1);
          PTh[o + kk0] = h0; PTl[o + kk0] = f2bf(p0 - bf2f(h0));
          PTh[o + kk1] = h1; PTl[o + kk1] = f2bf(p1 - bf2f(h1));
        }
      }
      // PV: A = P[m][k=n] frags via cvt_pk + lane^32 exchange
#pragma unroll
      for (int kc = 0; kc < 2; kc++) {
        bf16x8 paH[2], paL[2];
#pragma unroll
        for (int mt = 0; mt < 2; mt++) {
          float pq[8], lq[8];
#pragma unroll
          for (int qi = 0; qi < 8; qi++) {
            float v = (mt == 0) ? sa0[kc * 8 + qi] : sa1[kc * 8 + qi];
            unsigned short ph_ = f2bf(v);
            pq[qi] = v;
            lq[qi] = v - bf2f(ph_);
          }
          int c01 = (int)cvtpk(pq[0], pq[1]), c23 = (int)cvtpk(pq[2], pq[3]);
          int c45 = (int)cvtpk(pq[4], pq[5]), c67 = (int)cvtpk(pq[6], pq[7]);
          int d01 = __shfl_xor(c01, 32), d23 = __shfl_xor(c23, 32);
          int d45 = __shfl_xor(c45, 32), d67 = __shfl_xor(c67, 32);
          u32x4 wv;
          wv.x = (unsigned int)(hi ? d45 : c01);
          wv.y = (unsigned int)(hi ? d67 : c23);
          wv.z = (unsigned int)(hi ? c45 : d01);
          wv.w = (unsigned int)(hi ? c67 : d23);
          paH[mt] = __builtin_bit_cast(bf16x8, wv);
          int e01 = (int)cvtpk(lq[0], lq[1]), e23 = (int)cvtpk(lq[2], lq[3]);
          int e45 = (int)cvtpk(lq[4], lq[5]), e67 = (int)cvtpk(lq[6], lq[7]);
          int f01 = __shfl_xor(e01, 32), f23 = __shfl_xor(e23, 32);
          int f45 = __shfl_xor(e45, 32), f67 = __shfl_xor(e67, 32);
          u32x4 lv;
          lv.x = (unsigned int)(hi ? f45 : e01);
          lv.y = (unsigned int)(hi ? f67 : e23);
          lv.z = (unsigned int)(hi ? e45 : f01);
          lv.w = (unsigned int)(hi ? e67 : f23);
          paL[mt] = __builtin_bit_cast(bf16x8, lv);
        }
#pragma unroll
        for (int dt = 0; dt < 2; dt++) {
          bf16x8 vh, vl;
#pragma unroll
          for (int j = 0; j < 8; j++) {
            size_t vo = ((size_t)(b * 4096 + nb + kc * 16 + hi * 8 + j)) * 512 +
                        h * 64 + dt * 32 + lm;
            vh[j] = (short)projh[vo];
            vl[j] = (short)projl[vo];
          }
          pv[0][dt] = MFMA32(paH[0], vh, pv[0][dt]);
          pv[0][dt] = MFMA32(paH[0], vl, pv[0][dt]);
          pv[0][dt] = MFMA32(paL[0], vh, pv[0][dt]);
          pv[1][dt] = MFMA32(paH[1], vh, pv[1][dt]);
          pv[1][dt] = MFMA32(paH[1], vl, pv[1][dt]);
          pv[1][dt] = MFMA32(paL[1], vh, pv[1][dt]);
        }
      }
    }
  }
  // merge l across lane halves (each half summed a disjoint n-subset)
  lsum0 += __shfl_xor(lsum0, 32);
  lsum1 += __shfl_xor(lsum1, 32);
  __shared__ float pvbuf[64][64];
  __shared__ float lbuf[4][64];
  if (hi == 0) { lbuf[wave][lm] = lsum0; lbuf[wave][32 + lm] = lsum1; }
  // sequential PV merge across waves
  for (int w = 0; w < 4; w++) {
    __syncthreads();
    if (wave == w) {
#pragma unroll
      for (int mt = 0; mt < 2; mt++)
#pragma unroll
        for (int dt = 0; dt < 2; dt++)
#pragma unroll
          for (int r = 0; r < 16; r++) {
            int m = mt * 32 + (r & 3) + 8 * (r >> 2) + 4 * hi;
            int d = dt * 32 + lm;
            if (w == 0) pvbuf[m][d] = pv[mt][dt][r];
            else pvbuf[m][d] += pv[mt][dt][r];
          }
    }
  }
  __syncthreads();
  size_t base = ((size_t)(s * 64 + bh)) * 4096;
  for (int idx = t; idx < 4096; idx += 256)
    pvpart[base + idx] = pvbuf[idx >> 6][idx & 63];
  if (t < 64)
    lpart[((size_t)(s * 64 + bh)) * 64 + t] =
        lbuf[0][t] + lbuf[1][t] + lbuf[2][t] + lbuf[3][t];
}

// ---------------------------------------------------------------------------
// merge: rep2 = rep + step_rep * (sum_s PV_s) / (sum_s l_s);  linv = 1/l
// ---------------------------------------------------------------------------
__global__ __launch_bounds__(256) void merge_k(
    const float* __restrict__ pvpart, const float* __restrict__ lpart,
    const unsigned short* __restrict__ reph, const unsigned short* __restrict__ repl,
    const float* __restrict__ step_rep, float* __restrict__ rep2,
    float* __restrict__ linv) {
  int bh = blockIdx.x;
  int b = bh >> 3, h = bh & 7;
  float sr = step_rep[h];
  int t = threadIdx.x;
  __shared__ float lt[64];
  if (t < 64) {
    float L = 0.0f;
#pragma unroll
    for (int ss = 0; ss < 8; ss++) L += lpart[((size_t)(ss * 64 + bh)) * 64 + t];
    float inv = 1.0f / L;
    lt[t] = inv;
    linv[bh * 64 + t] = inv;
  }
  __syncthreads();
  for (int idx = t; idx < 4096; idx += 256) {
    int m = idx >> 6, d = idx & 63;
    float sum = 0.0f;
#pragma unroll
    for (int ss = 0; ss < 8; ss++)
      sum += pvpart[((size_t)(ss * 64 + bh)) * 4096 + idx];
    size_t ro = ((size_t)(b * 64 + m)) * 512 + h * 64 + d;
    float repv = bf2f(reph[ro]) + bf2f(repl[ro]);
    rep2[(size_t)bh * 4096 + idx] = repv + sr * sum * lt[m];
  }
}

// ---------------------------------------------------------------------------
// stage-2 self-attn among 64 tokens; writes GT' = (step_x/l) * xd2 @ Wo slice,
// split-bf16, k-contiguous: GT[b][co][k=h*64+m]
// ---------------------------------------------------------------------------
__global__ __launch_bounds__(256) void stage2_k(
    const float* __restrict__ rep2, const float* __restrict__ Wo,
    const float* __restrict__ step_x, const float* __restrict__ linv,
    unsigned short* __restrict__ GTh, unsigned short* __restrict__ GTl) {
  __shared__ float T[64][68];
  __shared__ float P[64][68];
  __shared__ float Wl[64][68];
  int bh = blockIdx.x, h = bh & 7, b = bh >> 3;
  int t = threadIdx.x;
  int mi = t >> 2, dq = (t & 3) * 16;
#pragma unroll
  for (int j = 0; j < 4; j++) {
    float4 v = *(const float4*)(rep2 + ((size_t)bh * 64 + mi) * 64 + dq + j * 4);
    T[dq + j * 4 + 0][mi] = v.x; T[dq + j * 4 + 1][mi] = v.y;
    T[dq + j * 4 + 2][mi] = v.z; T[dq + j * 4 + 3][mi] = v.w;
  }
  __syncthreads();
  int tx = t & 15, ty = t >> 4;
  {
    float acc[4][4] = {};
#pragma unroll
    for (int k = 0; k < 64; k++) {
      float4 a = *(const float4*)&T[k][ty * 4];
      float4 bv = *(const float4*)&T[k][tx * 4];
      float aa[4] = {a.x, a.y, a.z, a.w};
      float bb[4] = {bv.x, bv.y, bv.z, bv.w};
#pragma unroll
      for (int i = 0; i < 4; i++)
#pragma unroll
        for (int j = 0; j < 4; j++) acc[i][j] += aa[i] * bb[j];
    }
#pragma unroll
    for (int i = 0; i < 4; i++)
      *(float4*)&P[ty * 4 + i][tx * 4] =
          make_float4(acc[i][0] * SCALE, acc[i][1] * SCALE, acc[i][2] * SCALE,
                      acc[i][3] * SCALE);
  }
  __syncthreads();
  if (t < 64) {
    float mx = -3.4e38f;
    for (int n = 0; n < 64; n++) mx = fmaxf(mx, P[t][n]);
    float s = 0.0f;
    for (int n = 0; n < 64; n++) {
      float e = __expf(P[t][n] - mx);
      P[t][n] = e;
      s += e;
    }
    float r = 1.0f / s;
    for (int n = 0; n < 64; n++) P[t][n] *= r;
  }
  __syncthreads();
  float xacc[4][4] = {};
#pragma unroll
  for (int k = 0; k < 64; k++) {
    float aa[4], bb[4];
#pragma unroll
    for (int i = 0; i < 4; i++) {
      aa[i] = P[ty * 4 + i][k];
      bb[i] = T[tx * 4 + i][k];
    }
#pragma unroll
    for (int i = 0; i < 4; i++)
#pragma unroll
      for (int j = 0; j < 4; j++) xacc[i][j] += aa[i] * bb[j];
  }
  __syncthreads();
#pragma unroll
  for (int i = 0; i < 4; i++)
    *(float4*)&P[ty * 4 + i][tx * 4] =
        make_float4(xacc[i][0], xacc[i][1], xacc[i][2], xacc[i][3]);
  float sxh = step_x[h];
  float li[4];
#pragma unroll
  for (int i = 0; i < 4; i++) li[i] = linv[bh * 64 + ty * 4 + i] * sxh;
  int wk = t >> 2, wcq = (t & 3) * 16;
  for (int cb = 0; cb < 4; cb++) {
    __syncthreads();
#pragma unroll
    for (int j = 0; j < 4; j++)
      *(float4*)&Wl[wk][wcq + j * 4] =
          *(const float4*)(Wo + ((size_t)(h * 64 + wk)) * 256 + cb * 64 + wcq + j * 4);
    __syncthreads();
    float gacc[4][4] = {};
#pragma unroll
    for (int k = 0; k < 64; k++) {
      float aa[4];
#pragma unroll
      for (int i = 0; i < 4; i++) aa[i] = P[ty * 4 + i][k];
      float4 bv = *(const float4*)&Wl[k][tx * 4];
      float bb[4] = {bv.x, bv.y, bv.z, bv.w};
#pragma unroll
      for (int i = 0; i < 4; i++)
#pragma unroll
        for (int j = 0; j < 4; j++) gacc[i][j] += aa[i] * bb[j];
    }
#pragma unroll
    for (int i = 0; i < 4; i++)
#pragma unroll
      for (int j = 0; j < 4; j++) {
        float val = gacc[i][j] * li[i];
        size_t o = ((size_t)(b * 256 + cb * 64 + tx * 4 + j)) * 512 + h * 64 + ty * 4 + i;
        unsigned short hh, ll;
        split2(val, hh, ll);
        GTh[o] = hh;
        GTl[o] = ll;
      }
  }
}

extern "C" void kernel_launch(void* const* d_in, const int* in_sizes, int n_in,
                              void* d_out, int out_size, void* d_ws, size_t ws_size,
                              hipStream_t stream) {
  const float* x = (const float*)d_in[0];     // [8,256,4096]
  const float* Wp = (const float*)d_in[1];    // [256,512]
  const float* srep = (const float*)d_in[2];  // [8]
  const float* sx = (const float*)d_in[3];    // [8]
  const float* Wo = (const float*)d_in[4];    // [512,256]
  const float* bo = (const float*)d_in[5];    // [256]
  float* out = (float*)d_out;                 // [8,256,4096]

  char* wsb = (char*)d_ws;
  // -- persistent through fattn --
  unsigned short* projh = (unsigned short*)(wsb + 0);           // 33,554,432 B
  unsigned short* projl = (unsigned short*)(wsb + 33554432);    // 33,554,432 B
  unsigned short* xTh   = (unsigned short*)(wsb + 67108864);    // 16,777,216 B (dead after proj gemm)
  unsigned short* xTl   = (unsigned short*)(wsb + 83886080);    // 16,777,216 B
  unsigned short* PTh   = (unsigned short*)(wsb + 67108864);    // over xT (written in fattn)
  unsigned short* PTl   = (unsigned short*)(wsb + 100663296);   // 33,554,432 B
  unsigned short* WpTh  = (unsigned short*)(wsb + 100663296);   // over PTl head (dead before fattn)
  unsigned short* WpTl  = (unsigned short*)(wsb + 100925440);
  unsigned short* reph  = (unsigned short*)(wsb + 134217728);   // 524,288 B
  unsigned short* repl  = (unsigned short*)(wsb + 134742016);   // 524,288 B
  float*  pvpart        = (float*)(wsb + 135266304);            // 8,388,608 B
  float*  lpart         = (float*)(wsb + 143654912);            // 131,072 B -> end 143,785,984
  // -- aliases into proj region (proj dead after fattn) --
  float*  rep2          = (float*)(wsb + 0);                    // 1,048,576 B
  float*  linv          = (float*)(wsb + 1048576);              // 16,384 B
  unsigned short* GTh   = (unsigned short*)(wsb + 2097152);     // 2,097,152 B
  unsigned short* GTl   = (unsigned short*)(wsb + 4194304);     // 2,097,152 B

  // 1. x [b][256][4096] -> xT split [b][4096][256]
  tsplit<<<dim3(128, 8, 8), 256, 0, stream>>>(x, (long long)256 * 4096,
                                              xTh, xTl, (long long)4096 * 256, 256, 4096);
  // 2. Wp [256][512] -> WpT split [512][256]
  tsplit<<<dim3(16, 8, 1), 256, 0, stream>>>(Wp, 0, WpTh, WpTl, 0, 256, 512);
  // 3. proj = xT . WpT^T  (M=4096 N=512 K=256), split-bf16 output
  gemm_mfma<<<dim3(4, 32, 8), 256, 0, stream>>>(
      xTh, xTl, (long long)4096 * 256, WpTh, WpTl, 0,
      nullptr, projh, projl, (long long)4096 * 512, 4096, 512, 256, nullptr);
  // 4. pooled queries (split-bf16)
  pool2_k<<<dim3(512), 256, 0, stream>>>(projh, projl, reph, repl);
  // 5. fused attention
  fattn<<<dim3(64, 8), 256, 0, stream>>>(projh, projl, reph, repl, PTh, PTl,
                                         pvpart, lpart);
  // 6. merge partials -> rep2, linv
  merge_k<<<dim3(64), 256, 0, stream>>>(pvpart, lpart, reph, repl, srep, rep2, linv);
  // 7. stage-2 + fold step_x, W_out, 1/l -> GT split
  stage2_k<<<dim3(64), 256, 0, stream>>>(rep2, Wo, sx, linv, GTh, GTl);
  // 8. out = GT . PT^T + bias  (M=256 N=4096 K=512)
  gemm_mfma<<<dim3(32, 2, 8), 256, 0, stream>>>(
      GTh, GTl, (long long)256 * 512, PTh, PTl, (long long)4096 * 512,
      out, nullptr, nullptr, (long long)256 * 4096, 256, 4096, 512, bo);
}

// Round 4
// 236.670 us; speedup vs baseline: 1.7450x; 1.0716x over previous
//
#include <hip/hip_runtime.h>
#include <cstdint>
#include <cstddef>

// ---------------------------------------------------------------------------
// CBSA round 4: projT copy for coalesced V (via fused transpose+pool kernel),
// 2-phase double-buffered MFMA GEMMs, trimmed split-precision (K-lo/V-lo/P-lo
// dropped - error budget ~5e-4 worst case vs 8.1e-4 threshold).
// ---------------------------------------------------------------------------

#define SCALE 0.125f  // 64^-0.5

typedef __attribute__((ext_vector_type(8))) short bf16x8;    // 8 bf16 = 4 VGPR
typedef __attribute__((ext_vector_type(4))) float f32x4;
typedef __attribute__((ext_vector_type(16))) float f32x16;
typedef __attribute__((ext_vector_type(4))) unsigned int u32x4;

#define MFMA32(a, b, c) __builtin_amdgcn_mfma_f32_32x32x16_bf16(a, b, c, 0, 0, 0)
#define MFMA16(a, b, c) __builtin_amdgcn_mfma_f32_16x16x32_bf16(a, b, c, 0, 0, 0)

// ---- bf16 helpers (manual RNE; no NaN/inf in this workload) ----------------
__device__ __forceinline__ unsigned short f2bf(float x) {
  unsigned int u = __float_as_uint(x);
  u += 0x7FFFu + ((u >> 16) & 1u);
  return (unsigned short)(u >> 16);
}
__device__ __forceinline__ float bf2f(unsigned short b) {
  return __uint_as_float(((unsigned int)b) << 16);
}
__device__ __forceinline__ void split2(float x, unsigned short& h, unsigned short& l) {
  h = f2bf(x);
  l = f2bf(x - bf2f(h));
}
__device__ __forceinline__ unsigned int cvtpk(float lo, float hi_) {
  unsigned int r;
  asm("v_cvt_pk_bf16_f32 %0, %1, %2" : "=v"(r) : "v"(lo), "v"(hi_));
  return r;
}

// ---- async global->LDS, 16B per lane ---------------------------------------
typedef const __attribute__((address_space(1))) unsigned int* gas_ptr;
typedef __attribute__((address_space(3))) unsigned int* las_ptr;
__device__ __forceinline__ void gload16(const void* g, void* l) {
  __builtin_amdgcn_global_load_lds((gas_ptr)(size_t)g,
                                   (las_ptr)(unsigned int)(size_t)l, 16, 0, 0);
}

// ---------------------------------------------------------------------------
// transpose + bf16-split: in fp32 [bz][R][C] row-major -> oh/ol bf16 [bz][C][R]
// (vectorized 4B stores: each thread packs 2 consecutive output elements)
// ---------------------------------------------------------------------------
__global__ __launch_bounds__(256) void tsplit(
    const float* __restrict__ in, long long in_bs,
    unsigned short* __restrict__ oh, unsigned short* __restrict__ ol,
    long long o_bs, int R, int C) {
  __shared__ float T[32][33];
  int bz = blockIdx.z;
  const float* ip = in + (size_t)bz * in_bs;
  unsigned short* oph = oh + (size_t)bz * o_bs;
  unsigned short* opl = ol + (size_t)bz * o_bs;
  int c0 = blockIdx.x * 32, r0 = blockIdx.y * 32;
  int t = threadIdx.x;
  int col = t & 31, row8 = t >> 5;
#pragma unroll
  for (int i = 0; i < 4; i++)
    T[row8 + i * 8][col] = ip[(size_t)(r0 + row8 + i * 8) * C + c0 + col];
  __syncthreads();
  int cp = (t & 15) * 2, rr = t >> 4;
#pragma unroll
  for (int i = 0; i < 2; i++) {
    int orow = rr + i * 16;  // input col index (c0+orow) = output row
    float v0 = T[cp][orow], v1 = T[cp + 1][orow];
    unsigned short h0, l0, h1, l1;
    split2(v0, h0, l0);
    split2(v1, h1, l1);
    size_t o = (size_t)(c0 + orow) * R + r0 + cp;
    *(unsigned int*)(oph + o) = (unsigned int)h0 | ((unsigned int)h1 << 16);
    *(unsigned int*)(opl + o) = (unsigned int)l0 | ((unsigned int)l1 << 16);
  }
}

// ---------------------------------------------------------------------------
// Split-bf16 MFMA GEMM, 2-phase double-buffered staging + XCD swizzle.
// BT=2: C = (Ah+Al)*(Bh+Bl) 3-term. BT=1: C = (Ah+Al)*Bh 2-term.
// A bf16 [M][K], B bf16 [N][K], both K-contiguous. 128x128 tile, BK=32.
// 1D grid, decode: bx = id & (2^lnx-1), by = (id>>lnx)&(2^lny-1), bz = rest.
// ---------------------------------------------------------------------------
template <int BT>
__global__ __launch_bounds__(256) void gemm_mfma(
    const unsigned short* __restrict__ Ah, const unsigned short* __restrict__ Al,
    long long a_bs,
    const unsigned short* __restrict__ Bh, const unsigned short* __restrict__ Bl,
    long long b_bs,
    float* __restrict__ Cf, unsigned short* __restrict__ Ch,
    unsigned short* __restrict__ Cl, long long c_bs,
    int M, int N, int K, const float* __restrict__ bias, int lnx, int lny) {
  __shared__ unsigned short lds[2][4][128][32];  // 64 KB (2 bufs)
  // XCD-bijective swizzle (gridDim.x % 8 == 0 guaranteed by launch)
  int id0 = blockIdx.x;
  int cpx = gridDim.x >> 3;
  int id = (id0 & 7) * cpx + (id0 >> 3);
  int bx = id & ((1 << lnx) - 1);
  int by = (id >> lnx) & ((1 << lny) - 1);
  int bz = id >> (lnx + lny);
  int m0 = by * 128, n0 = bx * 128;
  int tid = threadIdx.x;
  int wave = tid >> 6, lane = tid & 63;
  int wr = wave >> 1, wc = wave & 1;

  // staging: wave w stages array w (BT=2) / waves 2,3 split Bh (BT=1).
  const unsigned short* src;
  int r0g, sBeg = 0, nS = 8, dArr = wave;
  if (wave == 0) {
    src = Ah + (size_t)bz * a_bs; r0g = m0;
  } else if (wave == 1) {
    src = Al + (size_t)bz * a_bs; r0g = m0;
  } else if (BT == 2) {
    src = ((wave == 2) ? Bh : Bl) + (size_t)bz * b_bs; r0g = n0;
  } else {
    src = Bh + (size_t)bz * b_bs; r0g = n0; dArr = 2;
    sBeg = (wave - 2) * 4; nS = 4;
  }
  int q = lane >> 2;
  int chunk = (lane & 3) ^ ((q >> 1) & 3);  // pre-swizzled global k-chunk
  const unsigned short* srow = src + (size_t)(r0g + q) * K + chunk * 8;

  // fragment read setup (swizzled ds_read slot matches the pre-swizzle)
  int g = lane >> 4, fr = lane & 15;
  int slot = (g ^ ((fr >> 1) & 3)) * 8;
  int offA = (wr * 64 + fr) * 32 + slot;           // within array 0
  int offB = 2 * 4096 + (wc * 64 + fr) * 32 + slot;  // within array 2

  f32x4 acc[4][4];
#pragma unroll
  for (int i = 0; i < 4; i++)
#pragma unroll
    for (int j = 0; j < 4; j++)
#pragma unroll
      for (int r = 0; r < 4; r++) acc[i][j][r] = 0.0f;

  int nt = K >> 5;
  // prologue: stage tile 0 into buf 0
  for (int s5 = 0; s5 < nS; ++s5) {
    int ss = sBeg + s5;
    gload16(srow + (size_t)(ss * 16) * K, &lds[0][dArr][ss * 16][0]);
  }
  __syncthreads();  // drain prologue loads
  int cur = 0;
  for (int t0 = 0; t0 < nt; ++t0) {
    if (t0 + 1 < nt) {  // issue next-tile loads into other buffer
      int k0 = (t0 + 1) << 5;
      for (int s5 = 0; s5 < nS; ++s5) {
        int ss = sBeg + s5;
        gload16(srow + (size_t)(ss * 16) * K + k0, &lds[cur ^ 1][dArr][ss * 16][0]);
      }
    }
    const unsigned short* bb = &lds[cur][0][0][0];
    bf16x8 af[2][4], bfv[2][4];
#pragma unroll
    for (int i = 0; i < 4; i++) {
      af[0][i] = *(const bf16x8*)(bb + offA + i * 512);
      af[1][i] = *(const bf16x8*)(bb + 4096 + offA + i * 512);
      bfv[0][i] = *(const bf16x8*)(bb + offB + i * 512);
      if (BT == 2) bfv[1][i] = *(const bf16x8*)(bb + 4096 + offB + i * 512);
    }
#pragma unroll
    for (int i = 0; i < 4; i++)
#pragma unroll
      for (int j = 0; j < 4; j++) {
        acc[i][j] = MFMA16(af[0][i], bfv[0][j], acc[i][j]);
        if (BT == 2) acc[i][j] = MFMA16(af[0][i], bfv[1][j], acc[i][j]);
        acc[i][j] = MFMA16(af[1][i], bfv[0][j], acc[i][j]);
      }
    __syncthreads();  // drains in-flight stage (vmcnt 0) + read-sync
    cur ^= 1;
  }
  // epilogue: D row = g*4 + reg, col = fr
  int mBase = m0 + wr * 64 + g * 4;
  int nBase = n0 + wc * 64 + fr;
  if (Cf) {
    float* Cb = Cf + (size_t)bz * c_bs;
#pragma unroll
    for (int i = 0; i < 4; i++)
#pragma unroll
      for (int qd = 0; qd < 4; qd++) {
        int m = mBase + i * 16 + qd;
        float bi = bias ? bias[m] : 0.0f;
#pragma unroll
        for (int j = 0; j < 4; j++)
          Cb[(size_t)m * N + nBase + j * 16] = acc[i][j][qd] + bi;
      }
  } else {
    unsigned short* Chb = Ch + (size_t)bz * c_bs;
    unsigned short* Clb = Cl + (size_t)bz * c_bs;
#pragma unroll
    for (int i = 0; i < 4; i++)
#pragma unroll
      for (int qd = 0; qd < 4; qd++) {
        int m = mBase + i * 16 + qd;
#pragma unroll
        for (int j = 0; j < 4; j++) {
          unsigned short hh, ll;
          split2(acc[i][j][qd], hh, ll);
          Chb[(size_t)m * N + nBase + j * 16] = hh;
          Clb[(size_t)m * N + nBase + j * 16] = ll;
        }
      }
  }
}

// ---------------------------------------------------------------------------
// tpool: stream proj (split) once; emit projTh = proj^T (bf16 hi, [b][i][n],
// n-contiguous for coalesced V loads) AND pooled rep (h+l, full precision).
// Block = (ch-tile 64, row-block py, batch b); 8 dy-subtiles of [64 n][64 ch].
// LDS transpose with XOR swizzle sw(ch) = ((ch ^ ch>>3)&7)<<3 (conflict-free).
// ---------------------------------------------------------------------------
__global__ __launch_bounds__(256) void tpool(
    const unsigned short* __restrict__ projh, const unsigned short* __restrict__ projl,
    unsigned short* __restrict__ projTh,
    unsigned short* __restrict__ reph, unsigned short* __restrict__ repl) {
  __shared__ unsigned short Lh[64][64];
  __shared__ unsigned short Ll[64][64];
  int it = blockIdx.x, py = blockIdx.y, b = blockIdx.z;
  int t = threadIdx.x;
  // read-phase identity
  int ch = t & 63, seg = t >> 6;  // seg 0..3 -> n-local [seg*16, +16)
  int swc = ((ch ^ (ch >> 3)) & 7) << 3;
  float poolacc[2] = {0.0f, 0.0f};

  for (int dy = 0; dy < 8; dy++) {
    int base_n = py * 512 + dy * 64;
    // ---- write phase: load [64 n][64 ch] (ch-contiguous), store transposed
    {
      int rl = t >> 3, cq = (t & 7) * 8;
#pragma unroll
      for (int p = 0; p < 2; p++) {
        int row = rl + p * 32;
        size_t ga = ((size_t)(b * 4096 + base_n + row)) * 512 + it * 64 + cq;
        bf16x8 vh = *(const bf16x8*)(projh + ga);
        bf16x8 vl = *(const bf16x8*)(projl + ga);
#pragma unroll
        for (int j = 0; j < 8; j++) {
          int cl = cq + j;
          int sw = ((cl ^ (cl >> 3)) & 7) << 3;
          Lh[cl][row ^ sw] = (unsigned short)vh[j];
          Ll[cl][row ^ sw] = (unsigned short)vl[j];
        }
      }
    }
    __syncthreads();
    // ---- read phase: per (ch, 8-n octet): write projTh + pool partials
#pragma unroll
    for (int half = 0; half < 2; half++) {
      int n0 = seg * 16 + half * 8;
      int n0x = n0 ^ swc;
      bf16x8 rh = *(const bf16x8*)&Lh[ch][n0x];
      bf16x8 rl8 = *(const bf16x8*)&Ll[ch][n0x];
      size_t o = ((size_t)(b * 512 + it * 64 + ch)) * 4096 + base_n + n0;
      *(bf16x8*)(projTh + o) = rh;
      float ssum = 0.0f;
#pragma unroll
      for (int j = 0; j < 8; j++)
        ssum += bf2f((unsigned short)rh[j]) + bf2f((unsigned short)rl8[j]);
      poolacc[half] += ssum;
    }
    __syncthreads();
  }
  // rep store: px = seg*2 + half
#pragma unroll
  for (int half = 0; half < 2; half++) {
    float v = poolacc[half] * 0.015625f;
    unsigned short hh, ll;
    split2(v, hh, ll);
    size_t ro = ((size_t)(b * 64 + py * 8 + seg * 2 + half)) * 512 + it * 64 + ch;
    reph[ro] = hh;
    repl[ro] = ll;
  }
}

// ---------------------------------------------------------------------------
// Fused attention: S^T = mfma(K, Qh+Ql) (K hi-only), P = exp(S*SCALE) (no
// max-sub; |arg| < ~0.8), PT stored hi-only transposed for the final GEMM,
// PV = (Ph+Pl)*Vh from projT (coalesced 16B loads), row-sums l.
// ---------------------------------------------------------------------------
__global__ __launch_bounds__(256) void fattn(
    const unsigned short* __restrict__ projh,
    const unsigned short* __restrict__ reph, const unsigned short* __restrict__ repl,
    const unsigned short* __restrict__ projTh,
    unsigned short* __restrict__ PTh,
    float* __restrict__ pvpart, float* __restrict__ lpart) {
  int bh = blockIdx.x, s = blockIdx.y;
  int b = bh >> 3, h = bh & 7;
  int t = threadIdx.x;
  int wave = t >> 6, lane = t & 63;
  int lm = lane & 31, hi = lane >> 5;

  // Q B-frags: col m = mt*32+lm, k = ks*16 + hi*8 + j
  bf16x8 qf[2][4][2];
#pragma unroll
  for (int mt = 0; mt < 2; mt++)
#pragma unroll
    for (int ks = 0; ks < 4; ks++) {
      size_t qo = ((size_t)(b * 64 + mt * 32 + lm)) * 512 + h * 64 + ks * 16 + hi * 8;
      qf[mt][ks][0] = *(const bf16x8*)(reph + qo);
      qf[mt][ks][1] = *(const bf16x8*)(repl + qo);
    }

  f32x16 pv[2][2];
#pragma unroll
  for (int a = 0; a < 2; a++)
#pragma unroll
    for (int c = 0; c < 2; c++)
#pragma unroll
      for (int r = 0; r < 16; r++) pv[a][c][r] = 0.0f;
  float lsum0 = 0.0f, lsum1 = 0.0f;

  for (int sti = 0; sti < 2; sti++) {
    int n0 = s * 512 + (wave * 2 + sti) * 64;
#pragma unroll
    for (int nn = 0; nn < 64; nn += 32) {
      int nb = n0 + nn;
      f32x16 sa0, sa1;
#pragma unroll
      for (int r = 0; r < 16; r++) { sa0[r] = 0.0f; sa1[r] = 0.0f; }
      __builtin_amdgcn_s_setprio(1);
#pragma unroll
      for (int ks = 0; ks < 4; ks++) {
        size_t ko = ((size_t)(b * 4096 + nb + lm)) * 512 + h * 64 + ks * 16 + hi * 8;
        bf16x8 kh = *(const bf16x8*)(projh + ko);
        sa0 = MFMA32(kh, qf[0][ks][0], sa0);
        sa0 = MFMA32(kh, qf[0][ks][1], sa0);
        sa1 = MFMA32(kh, qf[1][ks][0], sa1);
        sa1 = MFMA32(kh, qf[1][ks][1], sa1);
      }
      __builtin_amdgcn_s_setprio(0);
      // exp + row-sum partials
#pragma unroll
      for (int r = 0; r < 16; r++) {
        sa0[r] = __expf(sa0[r] * SCALE); lsum0 += sa0[r];
        sa1[r] = __expf(sa1[r] * SCALE); lsum1 += sa1[r];
      }
      // PT store (hi only): n = nb + (r&3)+8*(r>>2)+4*hi; k = h*64 + mt*32 + lm
      {
        int kk0 = h * 64 + lm, kk1 = kk0 + 32;
#pragma unroll
        for (int r = 0; r < 16; r++) {
          int n = nb + (r & 3) + 8 * (r >> 2) + 4 * hi;
          size_t o = ((size_t)(b * 4096 + n)) * 512;
          PTh[o + kk0] = f2bf(sa0[r]);
          PTh[o + kk1] = f2bf(sa1[r]);
        }
      }
      // PV: A = P[m][k=n] frags via cvt_pk + lane^32 exchange; B = Vh (projT)
#pragma unroll
      for (int kc = 0; kc < 2; kc++) {
        bf16x8 paH[2], paL[2];
#pragma unroll
        for (int mt = 0; mt < 2; mt++) {
          float pq[8], lq[8];
#pragma unroll
          for (int qi = 0; qi < 8; qi++) {
            float v = (mt == 0) ? sa0[kc * 8 + qi] : sa1[kc * 8 + qi];
            unsigned short ph_ = f2bf(v);
            pq[qi] = v;
            lq[qi] = v - bf2f(ph_);
          }
          int c01 = (int)cvtpk(pq[0], pq[1]), c23 = (int)cvtpk(pq[2], pq[3]);
          int c45 = (int)cvtpk(pq[4], pq[5]), c67 = (int)cvtpk(pq[6], pq[7]);
          int d01 = __shfl_xor(c01, 32), d23 = __shfl_xor(c23, 32);
          int d45 = __shfl_xor(c45, 32), d67 = __shfl_xor(c67, 32);
          u32x4 wv;
          wv.x = (unsigned int)(hi ? d45 : c01);
          wv.y = (unsigned int)(hi ? d67 : c23);
          wv.z = (unsigned int)(hi ? c45 : d01);
          wv.w = (unsigned int)(hi ? c67 : d23);
          paH[mt] = __builtin_bit_cast(bf16x8, wv);
          int e01 = (int)cvtpk(lq[0], lq[1]), e23 = (int)cvtpk(lq[2], lq[3]);
          int e45 = (int)cvtpk(lq[4], lq[5]), e67 = (int)cvtpk(lq[6], lq[7]);
          int f01 = __shfl_xor(e01, 32), f23 = __shfl_xor(e23, 32);
          int f45 = __shfl_xor(e45, 32), f67 = __shfl_xor(e67, 32);
          u32x4 lv;
          lv.x = (unsigned int)(hi ? f45 : e01);
          lv.y = (unsigned int)(hi ? f67 : e23);
          lv.z = (unsigned int)(hi ? e45 : f01);
          lv.w = (unsigned int)(hi ? e67 : f23);
          paL[mt] = __builtin_bit_cast(bf16x8, lv);
        }
#pragma unroll
        for (int dt = 0; dt < 2; dt++) {
          size_t vto = ((size_t)(b * 512 + h * 64 + dt * 32 + lm)) * 4096 +
                       nb + kc * 16 + hi * 8;
          bf16x8 vh = *(const bf16x8*)(projTh + vto);
          __builtin_amdgcn_s_setprio(1);
          pv[0][dt] = MFMA32(paH[0], vh, pv[0][dt]);
          pv[0][dt] = MFMA32(paL[0], vh, pv[0][dt]);
          pv[1][dt] = MFMA32(paH[1], vh, pv[1][dt]);
          pv[1][dt] = MFMA32(paL[1], vh, pv[1][dt]);
          __builtin_amdgcn_s_setprio(0);
        }
      }
    }
  }
  // merge l across lane halves (each half summed a disjoint n-subset)
  lsum0 += __shfl_xor(lsum0, 32);
  lsum1 += __shfl_xor(lsum1, 32);
  __shared__ float pvbuf[64][64];
  __shared__ float lbuf[4][64];
  if (hi == 0) { lbuf[wave][lm] = lsum0; lbuf[wave][32 + lm] = lsum1; }
  for (int w = 0; w < 4; w++) {
    __syncthreads();
    if (wave == w) {
#pragma unroll
      for (int mt = 0; mt < 2; mt++)
#pragma unroll
        for (int dt = 0; dt < 2; dt++)
#pragma unroll
          for (int r = 0; r < 16; r++) {
            int m = mt * 32 + (r & 3) + 8 * (r >> 2) + 4 * hi;
            int d = dt * 32 + lm;
            if (w == 0) pvbuf[m][d] = pv[mt][dt][r];
            else pvbuf[m][d] += pv[mt][dt][r];
          }
    }
  }
  __syncthreads();
  size_t base = ((size_t)(s * 64 + bh)) * 4096;
  for (int idx = t; idx < 4096; idx += 256)
    pvpart[base + idx] = pvbuf[idx >> 6][idx & 63];
  if (t < 64)
    lpart[((size_t)(s * 64 + bh)) * 64 + t] =
        lbuf[0][t] + lbuf[1][t] + lbuf[2][t] + lbuf[3][t];
}

// ---------------------------------------------------------------------------
// merge: rep2 = rep + step_rep * (sum_s PV_s) / (sum_s l_s);  linv = 1/l
// ---------------------------------------------------------------------------
__global__ __launch_bounds__(256) void merge_k(
    const float* __restrict__ pvpart, const float* __restrict__ lpart,
    const unsigned short* __restrict__ reph, const unsigned short* __restrict__ repl,
    const float* __restrict__ step_rep, float* __restrict__ rep2,
    float* __restrict__ linv) {
  int bh = blockIdx.x, qy = blockIdx.y;
  int b = bh >> 3, h = bh & 7;
  float sr = step_rep[h];
  int t = threadIdx.x;
  __shared__ float lt[64];
  if (t < 64) {
    float L = 0.0f;
#pragma unroll
    for (int ss = 0; ss < 8; ss++) L += lpart[((size_t)(ss * 64 + bh)) * 64 + t];
    float inv = 1.0f / L;
    lt[t] = inv;
    if (qy == 0) linv[bh * 64 + t] = inv;
  }
  __syncthreads();
#pragma unroll
  for (int k2 = 0; k2 < 4; k2++) {
    int idx = qy * 1024 + k2 * 256 + t;
    int m = idx >> 6, d = idx & 63;
    float sum = 0.0f;
#pragma unroll
    for (int ss = 0; ss < 8; ss++)
      sum += pvpart[((size_t)(ss * 64 + bh)) * 4096 + idx];
    size_t ro = ((size_t)(b * 64 + m)) * 512 + h * 64 + d;
    float repv = bf2f(reph[ro]) + bf2f(repl[ro]);
    rep2[(size_t)bh * 4096 + idx] = repv + sr * sum * lt[m];
  }
}

// ---------------------------------------------------------------------------
// stage-2 self-attn among 64 tokens; writes GT = (step_x/l)*xd2 @ Wo slice,
// split-bf16, k-contiguous: GT[b][co][k=h*64+m]
// ---------------------------------------------------------------------------
__global__ __launch_bounds__(256) void stage2_k(
    const float* __restrict__ rep2, const float* __restrict__ Wo,
    const float* __restrict__ step_x, const float* __restrict__ linv,
    unsigned short* __restrict__ GTh, unsigned short* __restrict__ GTl) {
  __shared__ float T[64][68];
  __shared__ float P[64][68];
  __shared__ float Wl[64][68];
  int bh = blockIdx.x, h = bh & 7, b = bh >> 3;
  int t = threadIdx.x;
  int mi = t >> 2, dq = (t & 3) * 16;
#pragma unroll
  for (int j = 0; j < 4; j++) {
    float4 v = *(const float4*)(rep2 + ((size_t)bh * 64 + mi) * 64 + dq + j * 4);
    T[dq + j * 4 + 0][mi] = v.x; T[dq + j * 4 + 1][mi] = v.y;
    T[dq + j * 4 + 2][mi] = v.z; T[dq + j * 4 + 3][mi] = v.w;
  }
  __syncthreads();
  int tx = t & 15, ty = t >> 4;
  {
    float acc[4][4] = {};
#pragma unroll
    for (int k = 0; k < 64; k++) {
      float4 a = *(const float4*)&T[k][ty * 4];
      float4 bv = *(const float4*)&T[k][tx * 4];
      float aa[4] = {a.x, a.y, a.z, a.w};
      float bb[4] = {bv.x, bv.y, bv.z, bv.w};
#pragma unroll
      for (int i = 0; i < 4; i++)
#pragma unroll
        for (int j = 0; j < 4; j++) acc[i][j] += aa[i] * bb[j];
    }
#pragma unroll
    for (int i = 0; i < 4; i++)
      *(float4*)&P[ty * 4 + i][tx * 4] =
          make_float4(acc[i][0] * SCALE, acc[i][1] * SCALE, acc[i][2] * SCALE,
                      acc[i][3] * SCALE);
  }
  __syncthreads();
  if (t < 64) {
    float mx = -3.4e38f;
    for (int n = 0; n < 64; n++) mx = fmaxf(mx, P[t][n]);
    float s = 0.0f;
    for (int n = 0; n < 64; n++) {
      float e = __expf(P[t][n] - mx);
      P[t][n] = e;
      s += e;
    }
    float r = 1.0f / s;
    for (int n = 0; n < 64; n++) P[t][n] *= r;
  }
  __syncthreads();
  float xacc[4][4] = {};
#pragma unroll
  for (int k = 0; k < 64; k++) {
    float aa[4], bb[4];
#pragma unroll
    for (int i = 0; i < 4; i++) {
      aa[i] = P[ty * 4 + i][k];
      bb[i] = T[tx * 4 + i][k];
    }
#pragma unroll
    for (int i = 0; i < 4; i++)
#pragma unroll
      for (int j = 0; j < 4; j++) xacc[i][j] += aa[i] * bb[j];
  }
  __syncthreads();
#pragma unroll
  for (int i = 0; i < 4; i++)
    *(float4*)&P[ty * 4 + i][tx * 4] =
        make_float4(xacc[i][0], xacc[i][1], xacc[i][2], xacc[i][3]);
  float sxh = step_x[h];
  float li[4];
#pragma unroll
  for (int i = 0; i < 4; i++) li[i] = linv[bh * 64 + ty * 4 + i] * sxh;
  int wk = t >> 2, wcq = (t & 3) * 16;
  for (int cb = 0; cb < 4; cb++) {
    __syncthreads();
#pragma unroll
    for (int j = 0; j < 4; j++)
      *(float4*)&Wl[wk][wcq + j * 4] =
          *(const float4*)(Wo + ((size_t)(h * 64 + wk)) * 256 + cb * 64 + wcq + j * 4);
    __syncthreads();
    float gacc[4][4] = {};
#pragma unroll
    for (int k = 0; k < 64; k++) {
      float aa[4];
#pragma unroll
      for (int i = 0; i < 4; i++) aa[i] = P[ty * 4 + i][k];
      float4 bv = *(const float4*)&Wl[k][tx * 4];
      float bb[4] = {bv.x, bv.y, bv.z, bv.w};
#pragma unroll
      for (int i = 0; i < 4; i++)
#pragma unroll
        for (int j = 0; j < 4; j++) gacc[i][j] += aa[i] * bb[j];
    }
#pragma unroll
    for (int i = 0; i < 4; i++)
#pragma unroll
      for (int j = 0; j < 4; j++) {
        float val = gacc[i][j] * li[i];
        size_t o = ((size_t)(b * 256 + cb * 64 + tx * 4 + j)) * 512 + h * 64 + ty * 4 + i;
        unsigned short hh, ll;
        split2(val, hh, ll);
        GTh[o] = hh;
        GTl[o] = ll;
      }
  }
}

extern "C" void kernel_launch(void* const* d_in, const int* in_sizes, int n_in,
                              void* d_out, int out_size, void* d_ws, size_t ws_size,
                              hipStream_t stream) {
  const float* x = (const float*)d_in[0];     // [8,256,4096]
  const float* Wp = (const float*)d_in[1];    // [256,512]
  const float* srep = (const float*)d_in[2];  // [8]
  const float* sx = (const float*)d_in[3];    // [8]
  const float* Wo = (const float*)d_in[4];    // [512,256]
  const float* bo = (const float*)d_in[5];    // [256]
  float* out = (float*)d_out;                 // [8,256,4096]

  char* wsb = (char*)d_ws;
  unsigned short* projh = (unsigned short*)(wsb + 0);           // 33.5 MB
  unsigned short* projl = (unsigned short*)(wsb + 33554432);    // 33.5 MB
  unsigned short* xTh   = (unsigned short*)(wsb + 67108864);    // 16.8 MB (dead after gemm1)
  unsigned short* xTl   = (unsigned short*)(wsb + 83886080);    // 16.8 MB (dead after gemm1)
  unsigned short* projTh= (unsigned short*)(wsb + 67108864);    // 33.5 MB (over xT; written by tpool)
  unsigned short* WpTh  = (unsigned short*)(wsb + 100663296);   // 0.26 MB (dead after gemm1)
  unsigned short* WpTl  = (unsigned short*)(wsb + 100925440);   // 0.26 MB
  unsigned short* PTh   = (unsigned short*)(wsb + 100663296);   // 33.5 MB (over WpT; written by fattn)
  unsigned short* reph  = (unsigned short*)(wsb + 134217728);   // 0.5 MB
  unsigned short* repl  = (unsigned short*)(wsb + 134742016);   // 0.5 MB
  float*  pvpart        = (float*)(wsb + 135266304);            // 8.4 MB
  float*  lpart         = (float*)(wsb + 143654912);            // 0.13 MB -> end 143.8 MB
  // aliases over proj (dead after fattn):
  float*  rep2          = (float*)(wsb + 0);                    // 1 MB
  float*  linv          = (float*)(wsb + 1048576);              // 16 KB
  unsigned short* GTh   = (unsigned short*)(wsb + 2097152);     // 2 MB
  unsigned short* GTl   = (unsigned short*)(wsb + 4194304);     // 2 MB

  // 1. x [b][256][4096] -> xT split [b][4096][256]
  tsplit<<<dim3(128, 8, 8), 256, 0, stream>>>(x, (long long)256 * 4096,
                                              xTh, xTl, (long long)4096 * 256, 256, 4096);
  // 2. Wp [256][512] -> WpT split [512][256]
  tsplit<<<dim3(16, 8, 1), 256, 0, stream>>>(Wp, 0, WpTh, WpTl, 0, 256, 512);
  // 3. proj = xT . WpT^T (M=4096 N=512 K=256), split-bf16 out; grid 4x32x8
  gemm_mfma<2><<<dim3(1024), 256, 0, stream>>>(
      xTh, xTl, (long long)4096 * 256, WpTh, WpTl, 0,
      nullptr, projh, projl, (long long)4096 * 512, 4096, 512, 256, nullptr,
      2, 5);
  // 4. transpose (projTh) + pooled queries (rep split)
  tpool<<<dim3(8, 8, 8), 256, 0, stream>>>(projh, projl, projTh, reph, repl);
  // 5. fused attention
  fattn<<<dim3(64, 8), 256, 0, stream>>>(projh, reph, repl, projTh, PTh,
                                         pvpart, lpart);
  // 6. merge partials -> rep2, linv
  merge_k<<<dim3(64, 4), 256, 0, stream>>>(pvpart, lpart, reph, repl, srep,
                                           rep2, linv);
  // 7. stage-2 + fold step_x, W_out, 1/l -> GT split
  stage2_k<<<dim3(64), 256, 0, stream>>>(rep2, Wo, sx, linv, GTh, GTl);
  // 8. out = (GTh+GTl) . PTh^T + bias (M=256 N=4096 K=512); grid 32x2x8
  gemm_mfma<1><<<dim3(512), 256, 0, stream>>>(
      GTh, GTl, (long long)256 * 512, PTh, nullptr, (long long)4096 * 512,
      out, nullptr, nullptr, (long long)256 * 4096, 256, 4096, 512, bo,
      5, 1);
}

// Round 5
// 231.173 us; speedup vs baseline: 1.7865x; 1.0238x over previous
//
#include <hip/hip_runtime.h>
#include <cstdint>
#include <cstddef>

// ---------------------------------------------------------------------------
// CBSA round 5: projl eliminated (pool from bf16-hi proj), gemm1 2-term,
// LDS-chunk coalesced GEMM epilogues, merge+stage2 fused.
// ---------------------------------------------------------------------------

#define SCALE 0.125f  // 64^-0.5

typedef __attribute__((ext_vector_type(8))) short bf16x8;    // 8 bf16 = 4 VGPR
typedef __attribute__((ext_vector_type(4))) float f32x4;
typedef __attribute__((ext_vector_type(16))) float f32x16;
typedef __attribute__((ext_vector_type(4))) unsigned int u32x4;

#define MFMA32(a, b, c) __builtin_amdgcn_mfma_f32_32x32x16_bf16(a, b, c, 0, 0, 0)
#define MFMA16(a, b, c) __builtin_amdgcn_mfma_f32_16x16x32_bf16(a, b, c, 0, 0, 0)

// ---- bf16 helpers (manual RNE; no NaN/inf in this workload) ----------------
__device__ __forceinline__ unsigned short f2bf(float x) {
  unsigned int u = __float_as_uint(x);
  u += 0x7FFFu + ((u >> 16) & 1u);
  return (unsigned short)(u >> 16);
}
__device__ __forceinline__ float bf2f(unsigned short b) {
  return __uint_as_float(((unsigned int)b) << 16);
}
__device__ __forceinline__ void split2(float x, unsigned short& h, unsigned short& l) {
  h = f2bf(x);
  l = f2bf(x - bf2f(h));
}
__device__ __forceinline__ unsigned int cvtpk(float lo, float hi_) {
  unsigned int r;
  asm("v_cvt_pk_bf16_f32 %0, %1, %2" : "=v"(r) : "v"(lo), "v"(hi_));
  return r;
}

// ---- async global->LDS, 16B per lane ---------------------------------------
typedef const __attribute__((address_space(1))) unsigned int* gas_ptr;
typedef __attribute__((address_space(3))) unsigned int* las_ptr;
__device__ __forceinline__ void gload16(const void* g, void* l) {
  __builtin_amdgcn_global_load_lds((gas_ptr)(size_t)g,
                                   (las_ptr)(unsigned int)(size_t)l, 16, 0, 0);
}

// ---------------------------------------------------------------------------
// transpose + bf16-split: in fp32 [bz][R][C] row-major -> oh/ol bf16 [bz][C][R]
// ---------------------------------------------------------------------------
__global__ __launch_bounds__(256) void tsplit(
    const float* __restrict__ in, long long in_bs,
    unsigned short* __restrict__ oh, unsigned short* __restrict__ ol,
    long long o_bs, int R, int C) {
  __shared__ float T[32][33];
  int bz = blockIdx.z;
  const float* ip = in + (size_t)bz * in_bs;
  unsigned short* oph = oh + (size_t)bz * o_bs;
  unsigned short* opl = ol + (size_t)bz * o_bs;
  int c0 = blockIdx.x * 32, r0 = blockIdx.y * 32;
  int t = threadIdx.x;
  int col = t & 31, row8 = t >> 5;
#pragma unroll
  for (int i = 0; i < 4; i++)
    T[row8 + i * 8][col] = ip[(size_t)(r0 + row8 + i * 8) * C + c0 + col];
  __syncthreads();
  int cp = (t & 15) * 2, rr = t >> 4;
#pragma unroll
  for (int i = 0; i < 2; i++) {
    int orow = rr + i * 16;
    float v0 = T[cp][orow], v1 = T[cp + 1][orow];
    unsigned short h0, l0, h1, l1;
    split2(v0, h0, l0);
    split2(v1, h1, l1);
    size_t o = (size_t)(c0 + orow) * R + r0 + cp;
    *(unsigned int*)(oph + o) = (unsigned int)h0 | ((unsigned int)h1 << 16);
    *(unsigned int*)(opl + o) = (unsigned int)l0 | ((unsigned int)l1 << 16);
  }
}

// ---------------------------------------------------------------------------
// Split-bf16 MFMA GEMM: C = (Ah+Al)[m][k] * Bh[n][k]  (2 MFMA per pair).
// 128x128 tile, BK=32, 2-phase double-buffered staging, XCD-bijective swizzle.
// Epilogue: per-wave LDS chunk -> coalesced wide stores.
// F32OUT: fp32 C + bias(M).  else: bf16-hi C.
// ---------------------------------------------------------------------------
template <bool F32OUT>
__global__ __launch_bounds__(256) void gemm_sb(
    const unsigned short* __restrict__ Ah, const unsigned short* __restrict__ Al,
    long long a_bs,
    const unsigned short* __restrict__ Bh, long long b_bs,
    float* __restrict__ Cf, unsigned short* __restrict__ Ch, long long c_bs,
    int M, int N, int K, const float* __restrict__ bias, int lnx, int lny) {
  __shared__ unsigned short lds[2][3][128][32];  // 48 KB (0=Ah 1=Al 2=Bh)
  int id0 = blockIdx.x;
  int cpx = gridDim.x >> 3;
  int id = (id0 & 7) * cpx + (id0 >> 3);
  int bx = id & ((1 << lnx) - 1);
  int by = (id >> lnx) & ((1 << lny) - 1);
  int bz = id >> (lnx + lny);
  int m0 = by * 128, n0 = bx * 128;
  int tid = threadIdx.x;
  int wave = tid >> 6, lane = tid & 63;
  int wr = wave >> 1, wc = wave & 1;

  const unsigned short* src;
  int r0g, sBeg, nS, dArr;
  if (wave == 0) { src = Ah + (size_t)bz * a_bs; r0g = m0; sBeg = 0; nS = 8; dArr = 0; }
  else if (wave == 1) { src = Al + (size_t)bz * a_bs; r0g = m0; sBeg = 0; nS = 8; dArr = 1; }
  else { src = Bh + (size_t)bz * b_bs; r0g = n0; sBeg = (wave - 2) * 4; nS = 4; dArr = 2; }
  int q = lane >> 2;
  int chunk = (lane & 3) ^ ((q >> 1) & 3);  // pre-swizzled global k-chunk
  const unsigned short* srow = src + (size_t)(r0g + q) * K + chunk * 8;

  int g = lane >> 4, fr = lane & 15;
  int slot = (g ^ ((fr >> 1) & 3)) * 8;
  int offA = (wr * 64 + fr) * 32 + slot;
  int offB = 2 * 4096 + (wc * 64 + fr) * 32 + slot;

  f32x4 acc[4][4];
#pragma unroll
  for (int i = 0; i < 4; i++)
#pragma unroll
    for (int j = 0; j < 4; j++)
#pragma unroll
      for (int r = 0; r < 4; r++) acc[i][j][r] = 0.0f;

  int nt = K >> 5;
  for (int s5 = 0; s5 < nS; ++s5) {
    int ss = sBeg + s5;
    gload16(srow + (size_t)(ss * 16) * K, &lds[0][dArr][ss * 16][0]);
  }
  __syncthreads();
  int cur = 0;
  for (int t0 = 0; t0 < nt; ++t0) {
    if (t0 + 1 < nt) {
      int k0 = (t0 + 1) << 5;
      for (int s5 = 0; s5 < nS; ++s5) {
        int ss = sBeg + s5;
        gload16(srow + (size_t)(ss * 16) * K + k0, &lds[cur ^ 1][dArr][ss * 16][0]);
      }
    }
    const unsigned short* bb = &lds[cur][0][0][0];
    bf16x8 af[2][4], bfv[4];
#pragma unroll
    for (int i = 0; i < 4; i++) {
      af[0][i] = *(const bf16x8*)(bb + offA + i * 512);
      af[1][i] = *(const bf16x8*)(bb + 4096 + offA + i * 512);
      bfv[i] = *(const bf16x8*)(bb + offB + i * 512);
    }
#pragma unroll
    for (int i = 0; i < 4; i++)
#pragma unroll
      for (int j = 0; j < 4; j++) {
        acc[i][j] = MFMA16(af[0][i], bfv[j], acc[i][j]);
        acc[i][j] = MFMA16(af[1][i], bfv[j], acc[i][j]);
      }
    __syncthreads();
    cur ^= 1;
  }

  // ---- epilogue: per-wave LDS chunk [16][68] fp32 -> coalesced stores ------
  float* eld = (float*)(&lds[0][0][0][0]) + wave * 1088;  // 16*68
  int rr = lane >> 2, cb = (lane & 3) * 16;
#pragma unroll
  for (int i = 0; i < 4; i++) {
#pragma unroll
    for (int j = 0; j < 4; j++)
#pragma unroll
      for (int qd = 0; qd < 4; qd++)
        eld[(g * 4 + qd) * 68 + fr + j * 16] = acc[i][j][qd];
    __syncthreads();
    int mrow = m0 + wr * 64 + i * 16 + rr;
    int ncol = n0 + wc * 64 + cb;
    float4 v0 = *(const float4*)(eld + rr * 68 + cb);
    float4 v1 = *(const float4*)(eld + rr * 68 + cb + 4);
    float4 v2 = *(const float4*)(eld + rr * 68 + cb + 8);
    float4 v3 = *(const float4*)(eld + rr * 68 + cb + 12);
    if (F32OUT) {
      float bi = bias ? bias[mrow] : 0.0f;
      float* Cb = Cf + (size_t)bz * c_bs + (size_t)mrow * N + ncol;
      *(float4*)(Cb + 0) = make_float4(v0.x + bi, v0.y + bi, v0.z + bi, v0.w + bi);
      *(float4*)(Cb + 4) = make_float4(v1.x + bi, v1.y + bi, v1.z + bi, v1.w + bi);
      *(float4*)(Cb + 8) = make_float4(v2.x + bi, v2.y + bi, v2.z + bi, v2.w + bi);
      *(float4*)(Cb + 12) = make_float4(v3.x + bi, v3.y + bi, v3.z + bi, v3.w + bi);
    } else {
      float vv[16] = {v0.x, v0.y, v0.z, v0.w, v1.x, v1.y, v1.z, v1.w,
                      v2.x, v2.y, v2.z, v2.w, v3.x, v3.y, v3.z, v3.w};
      bf16x8 p0, p1;
#pragma unroll
      for (int k = 0; k < 8; k++) {
        p0[k] = (short)f2bf(vv[k]);
        p1[k] = (short)f2bf(vv[8 + k]);
      }
      unsigned short* Cb = Ch + (size_t)bz * c_bs + (size_t)mrow * N + ncol;
      *(bf16x8*)(Cb + 0) = p0;
      *(bf16x8*)(Cb + 8) = p1;
    }
    __syncthreads();
  }
}

// ---------------------------------------------------------------------------
// tpool: stream projh once; emit projTh = proj^T ([b][i][n], n-contiguous)
// AND pooled rep (split h/l). LDS XOR-swizzled transpose, conflict-free.
// ---------------------------------------------------------------------------
__global__ __launch_bounds__(256) void tpool(
    const unsigned short* __restrict__ projh,
    unsigned short* __restrict__ projTh,
    unsigned short* __restrict__ reph, unsigned short* __restrict__ repl) {
  __shared__ unsigned short Lh[64][64];
  int it = blockIdx.x, py = blockIdx.y, b = blockIdx.z;
  int t = threadIdx.x;
  int ch = t & 63, seg = t >> 6;
  int swc = ((ch ^ (ch >> 3)) & 7) << 3;
  float poolacc[2] = {0.0f, 0.0f};

  for (int dy = 0; dy < 8; dy++) {
    int base_n = py * 512 + dy * 64;
    {
      int rl = t >> 3, cq = (t & 7) * 8;
#pragma unroll
      for (int p = 0; p < 2; p++) {
        int row = rl + p * 32;
        size_t ga = ((size_t)(b * 4096 + base_n + row)) * 512 + it * 64 + cq;
        bf16x8 vh = *(const bf16x8*)(projh + ga);
#pragma unroll
        for (int j = 0; j < 8; j++) {
          int cl = cq + j;
          int sw = ((cl ^ (cl >> 3)) & 7) << 3;
          Lh[cl][row ^ sw] = (unsigned short)vh[j];
        }
      }
    }
    __syncthreads();
#pragma unroll
    for (int half = 0; half < 2; half++) {
      int n0 = seg * 16 + half * 8;
      int n0x = n0 ^ swc;
      bf16x8 rh = *(const bf16x8*)&Lh[ch][n0x];
      size_t o = ((size_t)(b * 512 + it * 64 + ch)) * 4096 + base_n + n0;
      *(bf16x8*)(projTh + o) = rh;
      float ssum = 0.0f;
#pragma unroll
      for (int j = 0; j < 8; j++) ssum += bf2f((unsigned short)rh[j]);
      poolacc[half] += ssum;
    }
    __syncthreads();
  }
#pragma unroll
  for (int half = 0; half < 2; half++) {
    float v = poolacc[half] * 0.015625f;
    unsigned short hh, ll;
    split2(v, hh, ll);
    size_t ro = ((size_t)(b * 64 + py * 8 + seg * 2 + half)) * 512 + it * 64 + ch;
    reph[ro] = hh;
    repl[ro] = ll;
  }
}

// ---------------------------------------------------------------------------
// Fused attention (unchanged from round 4): S^T = mfma(K, Qh+Ql), P = exp,
// PT stored hi-only transposed, PV = (Ph+Pl)*Vh from projT, row-sums l.
// ---------------------------------------------------------------------------
__global__ __launch_bounds__(256) void fattn(
    const unsigned short* __restrict__ projh,
    const unsigned short* __restrict__ reph, const unsigned short* __restrict__ repl,
    const unsigned short* __restrict__ projTh,
    unsigned short* __restrict__ PTh,
    float* __restrict__ pvpart, float* __restrict__ lpart) {
  int bh = blockIdx.x, s = blockIdx.y;
  int b = bh >> 3, h = bh & 7;
  int t = threadIdx.x;
  int wave = t >> 6, lane = t & 63;
  int lm = lane & 31, hi = lane >> 5;

  bf16x8 qf[2][4][2];
#pragma unroll
  for (int mt = 0; mt < 2; mt++)
#pragma unroll
    for (int ks = 0; ks < 4; ks++) {
      size_t qo = ((size_t)(b * 64 + mt * 32 + lm)) * 512 + h * 64 + ks * 16 + hi * 8;
      qf[mt][ks][0] = *(const bf16x8*)(reph + qo);
      qf[mt][ks][1] = *(const bf16x8*)(repl + qo);
    }

  f32x16 pv[2][2];
#pragma unroll
  for (int a = 0; a < 2; a++)
#pragma unroll
    for (int c = 0; c < 2; c++)
#pragma unroll
      for (int r = 0; r < 16; r++) pv[a][c][r] = 0.0f;
  float lsum0 = 0.0f, lsum1 = 0.0f;

  for (int sti = 0; sti < 2; sti++) {
    int n0 = s * 512 + (wave * 2 + sti) * 64;
#pragma unroll
    for (int nn = 0; nn < 64; nn += 32) {
      int nb = n0 + nn;
      f32x16 sa0, sa1;
#pragma unroll
      for (int r = 0; r < 16; r++) { sa0[r] = 0.0f; sa1[r] = 0.0f; }
      __builtin_amdgcn_s_setprio(1);
#pragma unroll
      for (int ks = 0; ks < 4; ks++) {
        size_t ko = ((size_t)(b * 4096 + nb + lm)) * 512 + h * 64 + ks * 16 + hi * 8;
        bf16x8 kh = *(const bf16x8*)(projh + ko);
        sa0 = MFMA32(kh, qf[0][ks][0], sa0);
        sa0 = MFMA32(kh, qf[0][ks][1], sa0);
        sa1 = MFMA32(kh, qf[1][ks][0], sa1);
        sa1 = MFMA32(kh, qf[1][ks][1], sa1);
      }
      __builtin_amdgcn_s_setprio(0);
#pragma unroll
      for (int r = 0; r < 16; r++) {
        sa0[r] = __expf(sa0[r] * SCALE); lsum0 += sa0[r];
        sa1[r] = __expf(sa1[r] * SCALE); lsum1 += sa1[r];
      }
      {
        int kk0 = h * 64 + lm, kk1 = kk0 + 32;
#pragma unroll
        for (int r = 0; r < 16; r++) {
          int n = nb + (r & 3) + 8 * (r >> 2) + 4 * hi;
          size_t o = ((size_t)(b * 4096 + n)) * 512;
          PTh[o + kk0] = f2bf(sa0[r]);
          PTh[o + kk1] = f2bf(sa1[r]);
        }
      }
#pragma unroll
      for (int kc = 0; kc < 2; kc++) {
        bf16x8 paH[2], paL[2];
#pragma unroll
        for (int mt = 0; mt < 2; mt++) {
          float pq[8], lq[8];
#pragma unroll
          for (int qi = 0; qi < 8; qi++) {
            float v = (mt == 0) ? sa0[kc * 8 + qi] : sa1[kc * 8 + qi];
            unsigned short ph_ = f2bf(v);
            pq[qi] = v;
            lq[qi] = v - bf2f(ph_);
          }
          int c01 = (int)cvtpk(pq[0], pq[1]), c23 = (int)cvtpk(pq[2], pq[3]);
          int c45 = (int)cvtpk(pq[4], pq[5]), c67 = (int)cvtpk(pq[6], pq[7]);
          int d01 = __shfl_xor(c01, 32), d23 = __shfl_xor(c23, 32);
          int d45 = __shfl_xor(c45, 32), d67 = __shfl_xor(c67, 32);
          u32x4 wv;
          wv.x = (unsigned int)(hi ? d45 : c01);
          wv.y = (unsigned int)(hi ? d67 : c23);
          wv.z = (unsigned int)(hi ? c45 : d01);
          wv.w = (unsigned int)(hi ? c67 : d23);
          paH[mt] = __builtin_bit_cast(bf16x8, wv);
          int e01 = (int)cvtpk(lq[0], lq[1]), e23 = (int)cvtpk(lq[2], lq[3]);
          int e45 = (int)cvtpk(lq[4], lq[5]), e67 = (int)cvtpk(lq[6], lq[7]);
          int f01 = __shfl_xor(e01, 32), f23 = __shfl_xor(e23, 32);
          int f45 = __shfl_xor(e45, 32), f67 = __shfl_xor(e67, 32);
          u32x4 lv;
          lv.x = (unsigned int)(hi ? f45 : e01);
          lv.y = (unsigned int)(hi ? f67 : e23);
          lv.z = (unsigned int)(hi ? e45 : f01);
          lv.w = (unsigned int)(hi ? e67 : f23);
          paL[mt] = __builtin_bit_cast(bf16x8, lv);
        }
#pragma unroll
        for (int dt = 0; dt < 2; dt++) {
          size_t vto = ((size_t)(b * 512 + h * 64 + dt * 32 + lm)) * 4096 +
                       nb + kc * 16 + hi * 8;
          bf16x8 vh = *(const bf16x8*)(projTh + vto);
          __builtin_amdgcn_s_setprio(1);
          pv[0][dt] = MFMA32(paH[0], vh, pv[0][dt]);
          pv[0][dt] = MFMA32(paL[0], vh, pv[0][dt]);
          pv[1][dt] = MFMA32(paH[1], vh, pv[1][dt]);
          pv[1][dt] = MFMA32(paL[1], vh, pv[1][dt]);
          __builtin_amdgcn_s_setprio(0);
        }
      }
    }
  }
  lsum0 += __shfl_xor(lsum0, 32);
  lsum1 += __shfl_xor(lsum1, 32);
  __shared__ float pvbuf[64][64];
  __shared__ float lbuf[4][64];
  if (hi == 0) { lbuf[wave][lm] = lsum0; lbuf[wave][32 + lm] = lsum1; }
  for (int w = 0; w < 4; w++) {
    __syncthreads();
    if (wave == w) {
#pragma unroll
      for (int mt = 0; mt < 2; mt++)
#pragma unroll
        for (int dt = 0; dt < 2; dt++)
#pragma unroll
          for (int r = 0; r < 16; r++) {
            int m = mt * 32 + (r & 3) + 8 * (r >> 2) + 4 * hi;
            int d = dt * 32 + lm;
            if (w == 0) pvbuf[m][d] = pv[mt][dt][r];
            else pvbuf[m][d] += pv[mt][dt][r];
          }
    }
  }
  __syncthreads();
  size_t base = ((size_t)(s * 64 + bh)) * 4096;
  for (int idx = t; idx < 4096; idx += 256)
    pvpart[base + idx] = pvbuf[idx >> 6][idx & 63];
  if (t < 64)
    lpart[((size_t)(s * 64 + bh)) * 64 + t] =
        lbuf[0][t] + lbuf[1][t] + lbuf[2][t] + lbuf[3][t];
}

// ---------------------------------------------------------------------------
// Fused merge + stage-2: rep2 built straight into LDS (transposed), self-attn
// among 64 tokens, GT = (step_x/l)*xd2 @ Wo slice written split-bf16.
// ---------------------------------------------------------------------------
__global__ __launch_bounds__(256) void stage2f(
    const float* __restrict__ pvpart, const float* __restrict__ lpart,
    const unsigned short* __restrict__ reph, const unsigned short* __restrict__ repl,
    const float* __restrict__ step_rep, const float* __restrict__ step_x,
    const float* __restrict__ Wo,
    unsigned short* __restrict__ GTh, unsigned short* __restrict__ GTl) {
  __shared__ float T[64][68];
  __shared__ float P[64][68];
  __shared__ float Wl[64][68];
  __shared__ float lt[64];
  int bh = blockIdx.x, h = bh & 7, b = bh >> 3;
  int t = threadIdx.x;
  float sr = step_rep[h];
  if (t < 64) {
    float L = 0.0f;
#pragma unroll
    for (int ss = 0; ss < 8; ss++) L += lpart[((size_t)(ss * 64 + bh)) * 64 + t];
    lt[t] = 1.0f / L;
  }
  __syncthreads();
  for (int idx = t; idx < 4096; idx += 256) {
    int m = idx >> 6, d = idx & 63;
    float sum = 0.0f;
#pragma unroll
    for (int ss = 0; ss < 8; ss++)
      sum += pvpart[((size_t)(ss * 64 + bh)) * 4096 + idx];
    size_t ro = ((size_t)(b * 64 + m)) * 512 + h * 64 + d;
    float repv = bf2f(reph[ro]) + bf2f(repl[ro]);
    T[d][m] = repv + sr * sum * lt[m];
  }
  __syncthreads();
  int tx = t & 15, ty = t >> 4;
  {
    float acc[4][4] = {};
#pragma unroll
    for (int k = 0; k < 64; k++) {
      float4 a = *(const float4*)&T[k][ty * 4];
      float4 bv = *(const float4*)&T[k][tx * 4];
      float aa[4] = {a.x, a.y, a.z, a.w};
      float bb[4] = {bv.x, bv.y, bv.z, bv.w};
#pragma unroll
      for (int i = 0; i < 4; i++)
#pragma unroll
        for (int j = 0; j < 4; j++) acc[i][j] += aa[i] * bb[j];
    }
#pragma unroll
    for (int i = 0; i < 4; i++)
      *(float4*)&P[ty * 4 + i][tx * 4] =
          make_float4(acc[i][0] * SCALE, acc[i][1] * SCALE, acc[i][2] * SCALE,
                      acc[i][3] * SCALE);
  }
  __syncthreads();
  if (t < 64) {
    float mx = -3.4e38f;
    for (int n = 0; n < 64; n++) mx = fmaxf(mx, P[t][n]);
    float s = 0.0f;
    for (int n = 0; n < 64; n++) {
      float e = __expf(P[t][n] - mx);
      P[t][n] = e;
      s += e;
    }
    float r = 1.0f / s;
    for (int n = 0; n < 64; n++) P[t][n] *= r;
  }
  __syncthreads();
  float xacc[4][4] = {};
#pragma unroll
  for (int k = 0; k < 64; k++) {
    float aa[4], bb[4];
#pragma unroll
    for (int i = 0; i < 4; i++) {
      aa[i] = P[ty * 4 + i][k];
      bb[i] = T[tx * 4 + i][k];
    }
#pragma unroll
    for (int i = 0; i < 4; i++)
#pragma unroll
      for (int j = 0; j < 4; j++) xacc[i][j] += aa[i] * bb[j];
  }
  __syncthreads();
#pragma unroll
  for (int i = 0; i < 4; i++)
    *(float4*)&P[ty * 4 + i][tx * 4] =
        make_float4(xacc[i][0], xacc[i][1], xacc[i][2], xacc[i][3]);
  float sxh = step_x[h];
  float li[4];
#pragma unroll
  for (int i = 0; i < 4; i++) li[i] = lt[ty * 4 + i] * sxh;
  int wk = t >> 2, wcq = (t & 3) * 16;
  for (int cb = 0; cb < 4; cb++) {
    __syncthreads();
#pragma unroll
    for (int j = 0; j < 4; j++)
      *(float4*)&Wl[wk][wcq + j * 4] =
          *(const float4*)(Wo + ((size_t)(h * 64 + wk)) * 256 + cb * 64 + wcq + j * 4);
    __syncthreads();
    float gacc[4][4] = {};
#pragma unroll
    for (int k = 0; k < 64; k++) {
      float aa[4];
#pragma unroll
      for (int i = 0; i < 4; i++) aa[i] = P[ty * 4 + i][k];
      float4 bv = *(const float4*)&Wl[k][tx * 4];
      float bb[4] = {bv.x, bv.y, bv.z, bv.w};
#pragma unroll
      for (int i = 0; i < 4; i++)
#pragma unroll
        for (int j = 0; j < 4; j++) gacc[i][j] += aa[i] * bb[j];
    }
#pragma unroll
    for (int i = 0; i < 4; i++)
#pragma unroll
      for (int j = 0; j < 4; j++) {
        float val = gacc[i][j] * li[i];
        size_t o = ((size_t)(b * 256 + cb * 64 + tx * 4 + j)) * 512 + h * 64 + ty * 4 + i;
        unsigned short hh, ll;
        split2(val, hh, ll);
        GTh[o] = hh;
        GTl[o] = ll;
      }
  }
}

extern "C" void kernel_launch(void* const* d_in, const int* in_sizes, int n_in,
                              void* d_out, int out_size, void* d_ws, size_t ws_size,
                              hipStream_t stream) {
  const float* x = (const float*)d_in[0];     // [8,256,4096]
  const float* Wp = (const float*)d_in[1];    // [256,512]
  const float* srep = (const float*)d_in[2];  // [8]
  const float* sx = (const float*)d_in[3];    // [8]
  const float* Wo = (const float*)d_in[4];    // [512,256]
  const float* bo = (const float*)d_in[5];    // [256]
  float* out = (float*)d_out;                 // [8,256,4096]

  char* wsb = (char*)d_ws;
  unsigned short* projh  = (unsigned short*)(wsb + 0);          // 33.5 MB
  unsigned short* projTh = (unsigned short*)(wsb + 33554432);   // 33.5 MB
  unsigned short* xTh    = (unsigned short*)(wsb + 67108864);   // 16.8 MB (dead after gemm1)
  unsigned short* xTl    = (unsigned short*)(wsb + 83886080);   // 16.8 MB (dead after gemm1)
  unsigned short* PTh    = (unsigned short*)(wsb + 67108864);   // 33.5 MB over xT (fattn writes)
  unsigned short* WpTh   = (unsigned short*)(wsb + 100663296);  // 0.26 MB
  unsigned short* WpTl   = (unsigned short*)(wsb + 100925440);  // 0.26 MB (unused downstream)
  unsigned short* reph   = (unsigned short*)(wsb + 101187584);  // 0.5 MB
  unsigned short* repl   = (unsigned short*)(wsb + 101711872);  // 0.5 MB
  float* pvpart          = (float*)(wsb + 102236160);           // 8.4 MB
  float* lpart           = (float*)(wsb + 110624768);           // 0.13 MB
  unsigned short* GTh    = (unsigned short*)(wsb + 110755840);  // 2 MB
  unsigned short* GTl    = (unsigned short*)(wsb + 112852992);  // 2 MB -> end 114.95 MB

  // 1. x [b][256][4096] -> xT split [b][4096][256]
  tsplit<<<dim3(128, 8, 8), 256, 0, stream>>>(x, (long long)256 * 4096,
                                              xTh, xTl, (long long)4096 * 256, 256, 4096);
  // 2. Wp [256][512] -> WpT split [512][256] (only hi used downstream)
  tsplit<<<dim3(16, 8, 1), 256, 0, stream>>>(Wp, 0, WpTh, WpTl, 0, 256, 512);
  // 3. proj = (xTh+xTl) . WpTh^T  (M=4096 N=512 K=256) -> projh bf16
  gemm_sb<false><<<dim3(1024), 256, 0, stream>>>(
      xTh, xTl, (long long)4096 * 256, WpTh, 0,
      nullptr, projh, (long long)4096 * 512, 4096, 512, 256, nullptr, 2, 5);
  // 4. transpose (projTh) + pooled queries (rep split)
  tpool<<<dim3(8, 8, 8), 256, 0, stream>>>(projh, projTh, reph, repl);
  // 5. fused attention
  fattn<<<dim3(64, 8), 256, 0, stream>>>(projh, reph, repl, projTh, PTh,
                                         pvpart, lpart);
  // 6+7. merge partials + stage-2 -> GT split
  stage2f<<<dim3(64), 256, 0, stream>>>(pvpart, lpart, reph, repl, srep, sx,
                                        Wo, GTh, GTl);
  // 8. out = (GTh+GTl) . PTh^T + bias (M=256 N=4096 K=512)
  gemm_sb<true><<<dim3(512), 256, 0, stream>>>(
      GTh, GTl, (long long)256 * 512, PTh, (long long)4096 * 512,
      out, nullptr, (long long)256 * 4096, 256, 4096, 512, bo, 5, 1);
}

// Round 8
// 211.535 us; speedup vs baseline: 1.9523x; 1.0928x over previous
//
#include <hip/hip_runtime.h>
#include <cstdint>
#include <cstddef>

// ---------------------------------------------------------------------------
// CBSA round 6 candidate (2nd resubmit; rounds 6-7 hit GPU-acquisition
// timeouts, never ran): 1-term GEMMs (proj/out rounding dominates anyway),
// BM=64 tiles for gemm2 (occupancy), fattn re-partitioned for half the VGPR
// state and 2x grid, tsplit hi-only + merged x/Wp launch.
// ---------------------------------------------------------------------------

#define SCALE 0.125f  // 64^-0.5

typedef __attribute__((ext_vector_type(8))) short bf16x8;    // 8 bf16 = 4 VGPR
typedef __attribute__((ext_vector_type(4))) float f32x4;
typedef __attribute__((ext_vector_type(16))) float f32x16;
typedef __attribute__((ext_vector_type(4))) unsigned int u32x4;

#define MFMA32(a, b, c) __builtin_amdgcn_mfma_f32_32x32x16_bf16(a, b, c, 0, 0, 0)
#define MFMA16(a, b, c) __builtin_amdgcn_mfma_f32_16x16x32_bf16(a, b, c, 0, 0, 0)

// ---- bf16 helpers (manual RNE; no NaN/inf in this workload) ----------------
__device__ __forceinline__ unsigned short f2bf(float x) {
  unsigned int u = __float_as_uint(x);
  u += 0x7FFFu + ((u >> 16) & 1u);
  return (unsigned short)(u >> 16);
}
__device__ __forceinline__ float bf2f(unsigned short b) {
  return __uint_as_float(((unsigned int)b) << 16);
}
__device__ __forceinline__ void split2(float x, unsigned short& h, unsigned short& l) {
  h = f2bf(x);
  l = f2bf(x - bf2f(h));
}
__device__ __forceinline__ unsigned int cvtpk(float lo, float hi_) {
  unsigned int r;
  asm("v_cvt_pk_bf16_f32 %0, %1, %2" : "=v"(r) : "v"(lo), "v"(hi_));
  return r;
}

// ---- async global->LDS, 16B per lane ---------------------------------------
typedef const __attribute__((address_space(1))) unsigned int* gas_ptr;
typedef __attribute__((address_space(3))) unsigned int* las_ptr;
__device__ __forceinline__ void gload16(const void* g, void* l) {
  __builtin_amdgcn_global_load_lds((gas_ptr)(size_t)g,
                                   (las_ptr)(unsigned int)(size_t)l, 16, 0, 0);
}

// ---------------------------------------------------------------------------
// transpose + bf16 (hi only): z<8 -> x batch z [256][4096] -> xTh [4096][256];
// z==8 (bx<16) -> Wp [256][512] -> WpTh [512][256].
// ---------------------------------------------------------------------------
__global__ __launch_bounds__(256) void tsplit9(
    const float* __restrict__ x, const float* __restrict__ Wp,
    unsigned short* __restrict__ xTh, unsigned short* __restrict__ WpTh) {
  __shared__ float T[32][33];
  int z = blockIdx.z;
  const float* ip;
  unsigned short* oph;
  int C;
  const int R = 256;
  if (z < 8) {
    ip = x + (size_t)z * 256 * 4096;
    oph = xTh + (size_t)z * 4096 * 256;
    C = 4096;
  } else {
    if (blockIdx.x >= 16) return;
    ip = Wp;
    oph = WpTh;
    C = 512;
  }
  int c0 = blockIdx.x * 32, r0 = blockIdx.y * 32;
  int t = threadIdx.x;
  int col = t & 31, row8 = t >> 5;
#pragma unroll
  for (int i = 0; i < 4; i++)
    T[row8 + i * 8][col] = ip[(size_t)(r0 + row8 + i * 8) * C + c0 + col];
  __syncthreads();
  int cp = (t & 15) * 2, rr = t >> 4;
#pragma unroll
  for (int i = 0; i < 2; i++) {
    int orow = rr + i * 16;
    unsigned short h0 = f2bf(T[cp][orow]);
    unsigned short h1 = f2bf(T[cp + 1][orow]);
    size_t o = (size_t)(c0 + orow) * R + r0 + cp;
    *(unsigned int*)(oph + o) = (unsigned int)h0 | ((unsigned int)h1 << 16);
  }
}

// ---------------------------------------------------------------------------
// 1-term bf16 MFMA GEMM: C = Ah[m][k] * Bh[n][k].  Tile BM x 128, BK=32,
// 2-phase double-buffered global_load_lds staging, XCD-bijective swizzle,
// LDS-chunk coalesced epilogue. F32OUT: fp32 + bias(M); else bf16-hi.
// ---------------------------------------------------------------------------
template <int BM, bool F32OUT>
__global__ __launch_bounds__(256) void gemm_1t(
    const unsigned short* __restrict__ Ah, long long a_bs,
    const unsigned short* __restrict__ Bh, long long b_bs,
    float* __restrict__ Cf, unsigned short* __restrict__ Ch, long long c_bs,
    int M, int N, int K, const float* __restrict__ bias, int lnx, int lny) {
  constexpr int ROWS = BM + 128;
  __shared__ unsigned short lds[2][ROWS * 32];
  int id0 = blockIdx.x;
  int cpx = gridDim.x >> 3;
  int id = (id0 & 7) * cpx + (id0 >> 3);
  int bx = id & ((1 << lnx) - 1);
  int by = (id >> lnx) & ((1 << lny) - 1);
  int bz = id >> (lnx + lny);
  int m0 = by * BM, n0 = bx * 128;
  int tid = threadIdx.x;
  int wave = tid >> 6, lane = tid & 63;
  int wr = wave >> 1, wc = wave & 1;

  const unsigned short* Ab = Ah + (size_t)bz * a_bs;
  const unsigned short* Bb = Bh + (size_t)bz * b_bs;
  int q = lane >> 2;
  int chunk = (lane & 3) ^ ((q >> 1) & 3);  // pre-swizzled global k-chunk

  constexpr int ASL = BM / 16;  // A slabs (16 rows each)
  constexpr int TOT = ASL + 8;  // + 8 B slabs
  int sl0 = wave * TOT / 4, myN = (wave + 1) * TOT / 4 - wave * TOT / 4;
  const unsigned short* sSrc[4];
  unsigned sLds[4];
  for (int i = 0; i < 4; ++i) {
    int sl = sl0 + i;
    if (i < myN) {
      if (sl < ASL) {
        sSrc[i] = Ab + (size_t)(m0 + sl * 16 + q) * K + chunk * 8;
        sLds[i] = (unsigned)(sl * 16) * 32;
      } else {
        int bs = sl - ASL;
        sSrc[i] = Bb + (size_t)(n0 + bs * 16 + q) * K + chunk * 8;
        sLds[i] = (unsigned)(BM + bs * 16) * 32;
      }
    } else {
      sSrc[i] = nullptr;
      sLds[i] = 0;
    }
  }

  int g = lane >> 4, fr = lane & 15;
  int slot = (g ^ ((fr >> 1) & 3)) * 8;
  int offA = (wr * (BM / 2) + fr) * 32 + slot;
  int offB = (BM + wc * 64 + fr) * 32 + slot;

  constexpr int MI = BM / 32;
  f32x4 acc[MI][4];
#pragma unroll
  for (int i = 0; i < MI; i++)
#pragma unroll
    for (int j = 0; j < 4; j++)
#pragma unroll
      for (int r = 0; r < 4; r++) acc[i][j][r] = 0.0f;

  int nt = K >> 5;
  for (int i = 0; i < myN; ++i) gload16(sSrc[i], &lds[0][sLds[i]]);
  __syncthreads();
  int cur = 0;
  for (int t0 = 0; t0 < nt; ++t0) {
    if (t0 + 1 < nt) {
      int k0 = (t0 + 1) << 5;
      for (int i = 0; i < myN; ++i)
        gload16(sSrc[i] + k0, &lds[cur ^ 1][sLds[i]]);
    }
    bf16x8 af[MI], bfv[4];
#pragma unroll
    for (int i = 0; i < MI; i++) af[i] = *(const bf16x8*)(&lds[cur][offA + i * 512]);
#pragma unroll
    for (int j = 0; j < 4; j++) bfv[j] = *(const bf16x8*)(&lds[cur][offB + j * 512]);
#pragma unroll
    for (int i = 0; i < MI; i++)
#pragma unroll
      for (int j = 0; j < 4; j++) acc[i][j] = MFMA16(af[i], bfv[j], acc[i][j]);
    __syncthreads();  // drains stage (vmcnt) + read-sync
    cur ^= 1;
  }

  // ---- epilogue: per-wave LDS chunk [16][68] fp32 -> coalesced stores ------
  float* eld = (float*)(&lds[0][0]) + wave * 1088;
  int rr2 = lane >> 2, cb2 = (lane & 3) * 16;
#pragma unroll
  for (int i = 0; i < MI; i++) {
#pragma unroll
    for (int j = 0; j < 4; j++)
#pragma unroll
      for (int qd = 0; qd < 4; qd++)
        eld[(g * 4 + qd) * 68 + fr + j * 16] = acc[i][j][qd];
    // per-wave-private chunk: ds dependency handles ordering
    int mrow = m0 + wr * (BM / 2) + i * 16 + rr2;
    int ncol = n0 + wc * 64 + cb2;
    float4 v0 = *(const float4*)(eld + rr2 * 68 + cb2);
    float4 v1 = *(const float4*)(eld + rr2 * 68 + cb2 + 4);
    float4 v2 = *(const float4*)(eld + rr2 * 68 + cb2 + 8);
    float4 v3 = *(const float4*)(eld + rr2 * 68 + cb2 + 12);
    if (F32OUT) {
      float bi = bias ? bias[mrow] : 0.0f;
      float* Cb = Cf + (size_t)bz * c_bs + (size_t)mrow * N + ncol;
      *(float4*)(Cb + 0) = make_float4(v0.x + bi, v0.y + bi, v0.z + bi, v0.w + bi);
      *(float4*)(Cb + 4) = make_float4(v1.x + bi, v1.y + bi, v1.z + bi, v1.w + bi);
      *(float4*)(Cb + 8) = make_float4(v2.x + bi, v2.y + bi, v2.z + bi, v2.w + bi);
      *(float4*)(Cb + 12) = make_float4(v3.x + bi, v3.y + bi, v3.z + bi, v3.w + bi);
    } else {
      float vv[16] = {v0.x, v0.y, v0.z, v0.w, v1.x, v1.y, v1.z, v1.w,
                      v2.x, v2.y, v2.z, v2.w, v3.x, v3.y, v3.z, v3.w};
      bf16x8 p0, p1;
#pragma unroll
      for (int k = 0; k < 8; k++) {
        p0[k] = (short)f2bf(vv[k]);
        p1[k] = (short)f2bf(vv[8 + k]);
      }
      unsigned short* Cb = Ch + (size_t)bz * c_bs + (size_t)mrow * N + ncol;
      *(bf16x8*)(Cb + 0) = p0;
      *(bf16x8*)(Cb + 8) = p1;
    }
    __syncthreads();  // keep LDS write/read phases disjoint across i
  }
}

// ---------------------------------------------------------------------------
// tpool: stream projh once; emit projTh = proj^T ([b][i][n]) AND pooled rep
// (split h/l). LDS XOR-swizzled transpose, conflict-free.
// ---------------------------------------------------------------------------
__global__ __launch_bounds__(256) void tpool(
    const unsigned short* __restrict__ projh,
    unsigned short* __restrict__ projTh,
    unsigned short* __restrict__ reph, unsigned short* __restrict__ repl) {
  __shared__ unsigned short Lh[64][64];
  int it = blockIdx.x, py = blockIdx.y, b = blockIdx.z;
  int t = threadIdx.x;
  int ch = t & 63, seg = t >> 6;
  int swc = ((ch ^ (ch >> 3)) & 7) << 3;
  float poolacc[2] = {0.0f, 0.0f};

  for (int dy = 0; dy < 8; dy++) {
    int base_n = py * 512 + dy * 64;
    {
      int rl = t >> 3, cq = (t & 7) * 8;
#pragma unroll
      for (int p = 0; p < 2; p++) {
        int row = rl + p * 32;
        size_t ga = ((size_t)(b * 4096 + base_n + row)) * 512 + it * 64 + cq;
        bf16x8 vh = *(const bf16x8*)(projh + ga);
#pragma unroll
        for (int j = 0; j < 8; j++) {
          int cl = cq + j;
          int sw = ((cl ^ (cl >> 3)) & 7) << 3;
          Lh[cl][row ^ sw] = (unsigned short)vh[j];
        }
      }
    }
    __syncthreads();
#pragma unroll
    for (int half = 0; half < 2; half++) {
      int n0 = seg * 16 + half * 8;
      int n0x = n0 ^ swc;
      bf16x8 rh = *(const bf16x8*)&Lh[ch][n0x];
      size_t o = ((size_t)(b * 512 + it * 64 + ch)) * 4096 + base_n + n0;
      *(bf16x8*)(projTh + o) = rh;
      float ssum = 0.0f;
#pragma unroll
      for (int j = 0; j < 8; j++) ssum += bf2f((unsigned short)rh[j]);
      poolacc[half] += ssum;
    }
    __syncthreads();
  }
#pragma unroll
  for (int half = 0; half < 2; half++) {
    float v = poolacc[half] * 0.015625f;
    unsigned short hh, ll;
    split2(v, hh, ll);
    size_t ro = ((size_t)(b * 64 + py * 8 + seg * 2 + half)) * 512 + it * 64 + ch;
    reph[ro] = hh;
    repl[ro] = ll;
  }
}

// ---------------------------------------------------------------------------
// Fused attention, re-partitioned: grid (bh=64, s=16); block = 256 keys.
// Wave w: mt = w&1 (32 q-rows), kh = w>>1 (128 keys). ~half the register
// state of round 5 -> __launch_bounds__(256,4) for 4 waves/SIMD.
// ---------------------------------------------------------------------------
__global__ __launch_bounds__(256, 4) void fattn(
    const unsigned short* __restrict__ projh,
    const unsigned short* __restrict__ reph, const unsigned short* __restrict__ repl,
    const unsigned short* __restrict__ projTh,
    unsigned short* __restrict__ PTh,
    float* __restrict__ pvpart, float* __restrict__ lpart) {
  int bh = blockIdx.x, s = blockIdx.y;
  int b = bh >> 3, h = bh & 7;
  int t = threadIdx.x;
  int wave = t >> 6, lane = t & 63;
  int lm = lane & 31, hi = lane >> 5;
  int mt = wave & 1, kh = wave >> 1;

  // Q B-frags for this wave's m-tile: col m = mt*32+lm, k = ks*16 + hi*8 + j
  bf16x8 qf[4][2];
#pragma unroll
  for (int ks = 0; ks < 4; ks++) {
    size_t qo = ((size_t)(b * 64 + mt * 32 + lm)) * 512 + h * 64 + ks * 16 + hi * 8;
    qf[ks][0] = *(const bf16x8*)(reph + qo);
    qf[ks][1] = *(const bf16x8*)(repl + qo);
  }

  f32x16 pv[2];
#pragma unroll
  for (int c = 0; c < 2; c++)
#pragma unroll
    for (int r = 0; r < 16; r++) pv[c][r] = 0.0f;
  float lsum = 0.0f;

  int n0 = s * 256 + kh * 128;
#pragma unroll
  for (int c4 = 0; c4 < 4; c4++) {
    int nb = n0 + c4 * 32;
    f32x16 sa;
#pragma unroll
    for (int r = 0; r < 16; r++) sa[r] = 0.0f;
    __builtin_amdgcn_s_setprio(1);
#pragma unroll
    for (int ks = 0; ks < 4; ks++) {
      size_t ko = ((size_t)(b * 4096 + nb + lm)) * 512 + h * 64 + ks * 16 + hi * 8;
      bf16x8 kh8 = *(const bf16x8*)(projh + ko);
      sa = MFMA32(kh8, qf[ks][0], sa);
      sa = MFMA32(kh8, qf[ks][1], sa);
    }
    __builtin_amdgcn_s_setprio(0);
#pragma unroll
    for (int r = 0; r < 16; r++) {
      sa[r] = __expf(sa[r] * SCALE);
      lsum += sa[r];
    }
    // PT store (hi only): n = nb + (r&3)+8*(r>>2)+4*hi; k = h*64 + mt*32 + lm
    {
      int kk = h * 64 + mt * 32 + lm;
#pragma unroll
      for (int r = 0; r < 16; r++) {
        int n = nb + (r & 3) + 8 * (r >> 2) + 4 * hi;
        PTh[((size_t)(b * 4096 + n)) * 512 + kk] = f2bf(sa[r]);
      }
    }
    // PV: A = P[m][k=n] frags via cvt_pk + lane^32 exchange; B = Vh (projT)
#pragma unroll
    for (int kc = 0; kc < 2; kc++) {
      bf16x8 paH, paL;
      {
        float pq[8], lq[8];
#pragma unroll
        for (int qi = 0; qi < 8; qi++) {
          float v = sa[kc * 8 + qi];
          unsigned short ph_ = f2bf(v);
          pq[qi] = v;
          lq[qi] = v - bf2f(ph_);
        }
        int c01 = (int)cvtpk(pq[0], pq[1]), c23 = (int)cvtpk(pq[2], pq[3]);
        int c45 = (int)cvtpk(pq[4], pq[5]), c67 = (int)cvtpk(pq[6], pq[7]);
        int d01 = __shfl_xor(c01, 32), d23 = __shfl_xor(c23, 32);
        int d45 = __shfl_xor(c45, 32), d67 = __shfl_xor(c67, 32);
        u32x4 wv;
        wv.x = (unsigned int)(hi ? d45 : c01);
        wv.y = (unsigned int)(hi ? d67 : c23);
        wv.z = (unsigned int)(hi ? c45 : d01);
        wv.w = (unsigned int)(hi ? c67 : d23);
        paH = __builtin_bit_cast(bf16x8, wv);
        int e01 = (int)cvtpk(lq[0], lq[1]), e23 = (int)cvtpk(lq[2], lq[3]);
        int e45 = (int)cvtpk(lq[4], lq[5]), e67 = (int)cvtpk(lq[6], lq[7]);
        int f01 = __shfl_xor(e01, 32), f23 = __shfl_xor(e23, 32);
        int f45 = __shfl_xor(e45, 32), f67 = __shfl_xor(e67, 32);
        u32x4 lv;
        lv.x = (unsigned int)(hi ? f45 : e01);
        lv.y = (unsigned int)(hi ? f67 : e23);
        lv.z = (unsigned int)(hi ? e45 : f01);
        lv.w = (unsigned int)(hi ? e67 : f23);
        paL = __builtin_bit_cast(bf16x8, lv);
      }
#pragma unroll
      for (int dt = 0; dt < 2; dt++) {
        size_t vto = ((size_t)(b * 512 + h * 64 + dt * 32 + lm)) * 4096 +
                     nb + kc * 16 + hi * 8;
        bf16x8 vh = *(const bf16x8*)(projTh + vto);
        __builtin_amdgcn_s_setprio(1);
        pv[dt] = MFMA32(paH, vh, pv[dt]);
        pv[dt] = MFMA32(paL, vh, pv[dt]);
        __builtin_amdgcn_s_setprio(0);
      }
    }
  }
  // merge l across lane halves (each half summed disjoint n)
  lsum += __shfl_xor(lsum, 32);
  __shared__ float pvbuf[64][64];
  __shared__ float lbuf[4][32];
  if (hi == 0) lbuf[wave][lm] = lsum;
  // sequential PV merge: waves 0,1 init their m-half; 2,3 accumulate
  for (int w = 0; w < 4; w++) {
    __syncthreads();
    if (wave == w) {
#pragma unroll
      for (int dt = 0; dt < 2; dt++)
#pragma unroll
        for (int r = 0; r < 16; r++) {
          int m = mt * 32 + (r & 3) + 8 * (r >> 2) + 4 * hi;
          int d = dt * 32 + lm;
          if (w < 2) pvbuf[m][d] = pv[dt][r];
          else pvbuf[m][d] += pv[dt][r];
        }
    }
  }
  __syncthreads();
  size_t base = ((size_t)(s * 64 + bh)) * 4096;
  for (int idx = t; idx < 4096; idx += 256)
    pvpart[base + idx] = pvbuf[idx >> 6][idx & 63];
  if (t < 64) {
    int mt2 = t >> 5, lm2 = t & 31;
    lpart[((size_t)(s * 64 + bh)) * 64 + t] = lbuf[mt2][lm2] + lbuf[2 + mt2][lm2];
  }
}

// ---------------------------------------------------------------------------
// Fused merge + stage-2: rep2 in LDS, self-attn among 64 tokens, GT (bf16-hi)
// = (step_x/l)*xd2 @ Wo slice, k-contiguous: GT[b][co][k=h*64+m].
// ---------------------------------------------------------------------------
__global__ __launch_bounds__(256) void stage2f(
    const float* __restrict__ pvpart, const float* __restrict__ lpart,
    const unsigned short* __restrict__ reph, const unsigned short* __restrict__ repl,
    const float* __restrict__ step_rep, const float* __restrict__ step_x,
    const float* __restrict__ Wo, unsigned short* __restrict__ GTh) {
  __shared__ float T[64][68];
  __shared__ float P[64][68];
  __shared__ float Wl[64][68];
  __shared__ float lt[64];
  int bh = blockIdx.x, h = bh & 7, b = bh >> 3;
  int t = threadIdx.x;
  float sr = step_rep[h];
  if (t < 64) {
    float L = 0.0f;
#pragma unroll
    for (int ss = 0; ss < 16; ss++) L += lpart[((size_t)(ss * 64 + bh)) * 64 + t];
    lt[t] = 1.0f / L;
  }
  __syncthreads();
  for (int idx = t; idx < 4096; idx += 256) {
    int m = idx >> 6, d = idx & 63;
    float sum = 0.0f;
#pragma unroll
    for (int ss = 0; ss < 16; ss++)
      sum += pvpart[((size_t)(ss * 64 + bh)) * 4096 + idx];
    size_t ro = ((size_t)(b * 64 + m)) * 512 + h * 64 + d;
    float repv = bf2f(reph[ro]) + bf2f(repl[ro]);
    T[d][m] = repv + sr * sum * lt[m];
  }
  __syncthreads();
  int tx = t & 15, ty = t >> 4;
  {
    float acc[4][4] = {};
#pragma unroll
    for (int k = 0; k < 64; k++) {
      float4 a = *(const float4*)&T[k][ty * 4];
      float4 bv = *(const float4*)&T[k][tx * 4];
      float aa[4] = {a.x, a.y, a.z, a.w};
      float bb[4] = {bv.x, bv.y, bv.z, bv.w};
#pragma unroll
      for (int i = 0; i < 4; i++)
#pragma unroll
        for (int j = 0; j < 4; j++) acc[i][j] += aa[i] * bb[j];
    }
#pragma unroll
    for (int i = 0; i < 4; i++)
      *(float4*)&P[ty * 4 + i][tx * 4] =
          make_float4(acc[i][0] * SCALE, acc[i][1] * SCALE, acc[i][2] * SCALE,
                      acc[i][3] * SCALE);
  }
  __syncthreads();
  if (t < 64) {
    float mx = -3.4e38f;
    for (int n = 0; n < 64; n++) mx = fmaxf(mx, P[t][n]);
    float s = 0.0f;
    for (int n = 0; n < 64; n++) {
      float e = __expf(P[t][n] - mx);
      P[t][n] = e;
      s += e;
    }
    float r = 1.0f / s;
    for (int n = 0; n < 64; n++) P[t][n] *= r;
  }
  __syncthreads();
  float xacc[4][4] = {};
#pragma unroll
  for (int k = 0; k < 64; k++) {
    float aa[4], bb[4];
#pragma unroll
    for (int i = 0; i < 4; i++) {
      aa[i] = P[ty * 4 + i][k];
      bb[i] = T[tx * 4 + i][k];
    }
#pragma unroll
    for (int i = 0; i < 4; i++)
#pragma unroll
      for (int j = 0; j < 4; j++) xacc[i][j] += aa[i] * bb[j];
  }
  __syncthreads();
#pragma unroll
  for (int i = 0; i < 4; i++)
    *(float4*)&P[ty * 4 + i][tx * 4] =
        make_float4(xacc[i][0], xacc[i][1], xacc[i][2], xacc[i][3]);
  float sxh = step_x[h];
  float li[4];
#pragma unroll
  for (int i = 0; i < 4; i++) li[i] = lt[ty * 4 + i] * sxh;
  int wk = t >> 2, wcq = (t & 3) * 16;
  for (int cb = 0; cb < 4; cb++) {
    __syncthreads();
#pragma unroll
    for (int j = 0; j < 4; j++)
      *(float4*)&Wl[wk][wcq + j * 4] =
          *(const float4*)(Wo + ((size_t)(h * 64 + wk)) * 256 + cb * 64 + wcq + j * 4);
    __syncthreads();
    float gacc[4][4] = {};
#pragma unroll
    for (int k = 0; k < 64; k++) {
      float aa[4];
#pragma unroll
      for (int i = 0; i < 4; i++) aa[i] = P[ty * 4 + i][k];
      float4 bv = *(const float4*)&Wl[k][tx * 4];
      float bb[4] = {bv.x, bv.y, bv.z, bv.w};
#pragma unroll
      for (int i = 0; i < 4; i++)
#pragma unroll
        for (int j = 0; j < 4; j++) gacc[i][j] += aa[i] * bb[j];
    }
#pragma unroll
    for (int i = 0; i < 4; i++)
#pragma unroll
      for (int j = 0; j < 4; j++) {
        float val = gacc[i][j] * li[i];
        size_t o = ((size_t)(b * 256 + cb * 64 + tx * 4 + j)) * 512 + h * 64 + ty * 4 + i;
        GTh[o] = f2bf(val);
      }
  }
}

extern "C" void kernel_launch(void* const* d_in, const int* in_sizes, int n_in,
                              void* d_out, int out_size, void* d_ws, size_t ws_size,
                              hipStream_t stream) {
  const float* x = (const float*)d_in[0];     // [8,256,4096]
  const float* Wp = (const float*)d_in[1];    // [256,512]
  const float* srep = (const float*)d_in[2];  // [8]
  const float* sx = (const float*)d_in[3];    // [8]
  const float* Wo = (const float*)d_in[4];    // [512,256]
  const float* bo = (const float*)d_in[5];    // [256]
  float* out = (float*)d_out;                 // [8,256,4096]

  char* wsb = (char*)d_ws;
  unsigned short* projh  = (unsigned short*)(wsb + 0);          // 33.5 MB
  unsigned short* projTh = (unsigned short*)(wsb + 33554432);   // 33.5 MB
  unsigned short* xTh    = (unsigned short*)(wsb + 67108864);   // 16.8 MB (dead after gemm1)
  unsigned short* PTh    = (unsigned short*)(wsb + 67108864);   // 33.5 MB over xTh (fattn writes)
  unsigned short* WpTh   = (unsigned short*)(wsb + 100663296);  // 0.26 MB
  unsigned short* reph   = (unsigned short*)(wsb + 100925440);  // 0.5 MB
  unsigned short* repl   = (unsigned short*)(wsb + 101449728);  // 0.5 MB
  float* pvpart          = (float*)(wsb + 101974016);           // 16.8 MB
  float* lpart           = (float*)(wsb + 118751232);           // 0.26 MB
  unsigned short* GTh    = (unsigned short*)(wsb + 119013376);  // 2 MB -> end ~121 MB

  // 1. x -> xTh [b][4096][256] bf16-hi; Wp -> WpTh [512][256] (z==8 plane)
  tsplit9<<<dim3(128, 8, 9), 256, 0, stream>>>(x, Wp, xTh, WpTh);
  // 2. proj = xTh . WpTh^T (M=4096 N=512 K=256) -> projh bf16
  gemm_1t<128, false><<<dim3(1024), 256, 0, stream>>>(
      xTh, (long long)4096 * 256, WpTh, 0,
      nullptr, projh, (long long)4096 * 512, 4096, 512, 256, nullptr, 2, 5);
  // 3. transpose (projTh) + pooled queries (rep split)
  tpool<<<dim3(8, 8, 8), 256, 0, stream>>>(projh, projTh, reph, repl);
  // 4. fused attention (16 key-chunks of 256)
  fattn<<<dim3(64, 16), 256, 0, stream>>>(projh, reph, repl, projTh, PTh,
                                          pvpart, lpart);
  // 5. merge partials + stage-2 -> GTh
  stage2f<<<dim3(64), 256, 0, stream>>>(pvpart, lpart, reph, repl, srep, sx,
                                        Wo, GTh);
  // 6. out = GTh . PTh^T + bias (M=256 N=4096 K=512), BM=64 tiles
  gemm_1t<64, true><<<dim3(1024), 256, 0, stream>>>(
      GTh, (long long)256 * 512, PTh, (long long)4096 * 512,
      out, nullptr, (long long)256 * 4096, 256, 4096, 512, bo, 5, 2);
}